// Round 3
// baseline (557.401 us; speedup 1.0000x reference)
//
#include <hip/hip_runtime.h>
#include <cstdint>
#include <cstddef>

typedef __bf16 bf16;
typedef __bf16 bf16x8 __attribute__((ext_vector_type(8)));
typedef __bf16 bf16x4 __attribute__((ext_vector_type(4)));
typedef float  f32x4  __attribute__((ext_vector_type(4)));

#define B_   32
#define S_   384
#define D_   512
#define H_   8
#define DH_  64
#define DFF_ 2048
#define NTOK (B_*S_)

__device__ __forceinline__ void gload16(const void* g, void* l){
  __builtin_amdgcn_global_load_lds((__attribute__((address_space(1))) uint32_t*)(g),
                                   (__attribute__((address_space(3))) uint32_t*)(l), 16, 0, 0);
}

// ---------------- weight transpose: fp32 [K,N] -> bf16 [N,K] ----------------
struct Ptr8 { const float* s[8]; };
__global__ __launch_bounds__(256) void transpose_w8(Ptr8 ps, bf16* dst){
  __shared__ float t[64][65];
  int w = blockIdx.z;
  const float* src = ps.s[w];
  bf16* d = dst + (size_t)w*512*512;
  int tr = blockIdx.y*64, tc = blockIdx.x*64;
  for (int i=threadIdx.x; i<4096; i+=256){ int r=i>>6, c=i&63; t[r][c] = src[(size_t)(tr+r)*512 + tc+c]; }
  __syncthreads();
  for (int i=threadIdx.x; i<4096; i+=256){ int c=i>>6, r=i&63; d[(size_t)(tc+c)*512 + tr+r] = (bf16)t[r][c]; }
}

__global__ __launch_bounds__(256) void transpose_rc(const float* __restrict__ src, bf16* __restrict__ dst,
                                                    int R, int C){
  __shared__ float t[64][65];
  int tr = blockIdx.y*64, tc = blockIdx.x*64;
  for (int i=threadIdx.x; i<4096; i+=256){ int r=i>>6, c=i&63; t[r][c] = src[(size_t)(tr+r)*C + tc+c]; }
  __syncthreads();
  for (int i=threadIdx.x; i<4096; i+=256){ int c=i>>6, r=i&63; dst[(size_t)(tc+c)*R + tr+r] = (bf16)t[r][c]; }
}

// v [BH][S][64] bf16 -> vt [BH][64][S] bf16
__global__ __launch_bounds__(256) void transpose_v(const bf16* __restrict__ src, bf16* __restrict__ dst){
  __shared__ bf16 t[64][65];
  int bh = blockIdx.y; int sb = blockIdx.x*64;
  const bf16* s = src + (size_t)bh*S_*DH_;
  bf16* d = dst + (size_t)bh*DH_*S_;
  for (int i=threadIdx.x; i<4096; i+=256){ int r=i>>6, c=i&63; t[r][c] = s[(size_t)(sb+r)*DH_ + c]; }
  __syncthreads();
  for (int i=threadIdx.x; i<4096; i+=256){ int c=i>>6, r=i&63; d[(size_t)c*S_ + sb + r] = t[r][c]; }
}

// ---------------- BN scale/shift precompute: bn(x) = x*sc + sh ----------------
struct Ptr16 { const float* p[16]; };
__global__ __launch_bounds__(512) void bn_prep(Ptr16 q, float* sc, float* sh){
  int i = blockIdx.x;      // bn index 0..3
  int n = threadIdx.x;     // 0..511
  float g = q.p[i*4+0][n];
  float b = q.p[i*4+1][n];
  float m = q.p[i*4+2][n];
  float v = q.p[i*4+3][n];
  float s = g * rsqrtf(v + 1e-3f);
  sc[i*512+n] = s;
  sh[i*512+n] = b - m*s;
}

// fp32 -> bf16, optional fused bn (sc!=null)
__global__ __launch_bounds__(256) void cvt_bn(const float* __restrict__ x, const float* __restrict__ sc,
                                              const float* __restrict__ sh, bf16* __restrict__ out){
  size_t e0 = ((size_t)blockIdx.x*256 + threadIdx.x)*4;
  int n0 = (int)(e0 & (D_-1));
  f32x4 xv = *(const f32x4*)(x + e0);
  bf16x4 ov;
  if (sc){
    #pragma unroll
    for (int j=0;j<4;j++) ov[j] = (bf16)(xv[j]*sc[n0+j] + sh[n0+j]);
  } else {
    #pragma unroll
    for (int j=0;j<4;j++) ov[j] = (bf16)xv[j];
  }
  *(bf16x4*)(out + e0) = ov;
}

// ---------------- 128x128 MFMA GEMM, bf16 A [M,K] x bf16 Wt [N,K], fp32 epilogue ----------------
// mode 0: out [M,N]; mode 1: head-split [B,H,S,dh] (bf16 out only).
__global__ __launch_bounds__(256,2) void gemm128(
    const bf16* __restrict__ A, const bf16* __restrict__ Wt,
    const float* __restrict__ bias, const float* __restrict__ residf,
    const float* __restrict__ bsc, const float* __restrict__ bsh,
    bf16* __restrict__ out, float* __restrict__ outf, float* __restrict__ out2f,
    int M, int N, int K, int relu, int mode)
{
  __shared__ bf16 As[128*32];
  __shared__ bf16 Bs[128*32];
  int tiles_n = N >> 7;
  int tm = blockIdx.x / tiles_n, tn = blockIdx.x % tiles_n;
  int m0 = tm<<7, n0 = tn<<7;
  int tid = threadIdx.x, wave = tid>>6, lane = tid&63;
  int lhi = lane>>4, llo = lane&15;
  int wm = (wave>>1)<<6, wn = (wave&1)<<6;
  f32x4 acc[4][4];
  #pragma unroll
  for (int i=0;i<4;i++)
    #pragma unroll
    for (int j=0;j<4;j++) acc[i][j] = (f32x4){0.f,0.f,0.f,0.f};

  int c0 = wave*2, c1 = wave*2+1;
  int ra0 = c0*16 + (lane>>2), ra1 = c1*16 + (lane>>2);
  int ke  = (lane&3)*8;
  const bf16* Abase = A  + (size_t)m0 * K;
  const bf16* Bbase = Wt + (size_t)n0 * K;

  for (int kt=0; kt<K; kt+=32){
    gload16(Abase + (size_t)ra0*K + kt + ke, (char*)As + c0*1024);
    gload16(Abase + (size_t)ra1*K + kt + ke, (char*)As + c1*1024);
    gload16(Bbase + (size_t)ra0*K + kt + ke, (char*)Bs + c0*1024);
    gload16(Bbase + (size_t)ra1*K + kt + ke, (char*)Bs + c1*1024);
    __syncthreads();
    bf16x8 af[4], bfr[4];
    #pragma unroll
    for (int i=0;i<4;i++) af[i]  = *(const bf16x8*)&As[(wm + i*16 + llo)*32 + lhi*8];
    #pragma unroll
    for (int j=0;j<4;j++) bfr[j] = *(const bf16x8*)&Bs[(wn + j*16 + llo)*32 + lhi*8];
    #pragma unroll
    for (int i=0;i<4;i++)
      #pragma unroll
      for (int j=0;j<4;j++)
        acc[i][j] = __builtin_amdgcn_mfma_f32_16x16x32_bf16(af[i], bfr[j], acc[i][j], 0,0,0);
    __syncthreads();
  }

  #pragma unroll
  for (int i=0;i<4;i++){
    #pragma unroll
    for (int r=0;r<4;r++){
      int gm = m0 + wm + i*16 + lhi*4 + r;
      #pragma unroll
      for (int j=0;j<4;j++){
        int gn = n0 + wn + j*16 + llo;
        float v = acc[i][j][r];
        if (bias)   v += bias[gn];
        if (residf) v += residf[(size_t)gm*N + gn];
        if (out2f)  out2f[(size_t)gm*N + gn] = v;
        if (bsc)    v = v*bsc[gn] + bsh[gn];
        if (relu)   v = fmaxf(v, 0.f);
        if (mode == 0){
          if (outf) outf[(size_t)gm*N + gn] = v;
          else      out [(size_t)gm*N + gn] = (bf16)v;
        } else {
          int h = gn >> 6, dd = gn & 63;
          int bb = gm / S_, ss = gm - bb*S_;
          out[(((size_t)(bb*H_ + h))*S_ + ss)*DH_ + dd] = (bf16)v;
        }
      }
    }
  }
}

// ---------------- flash attention (conservative staging, full barriers)
// Q [BH,S,64], K [BH,S,64], Vt [BH,64,S] -> out merged [B,S,512]   (all bf16)
__global__ __launch_bounds__(256,2) void attn(
    const bf16* __restrict__ Q, const bf16* __restrict__ Kx,
    const bf16* __restrict__ Vt, bf16* __restrict__ out, int causal)
{
  __shared__ bf16 Ks[64*64];   // [key][d]
  __shared__ bf16 Vs[64*64];   // [d][key]
  __shared__ bf16 Ps[4][16*64];
  int qb = blockIdx.x, bh = blockIdx.y;
  int b = bh >> 3, h = bh & 7;
  int tid = threadIdx.x, wave = tid>>6, lane = tid&63;
  int lhi = lane>>4, llo = lane&15;
  const bf16* Qb = Q  + (size_t)bh*S_*DH_;
  const bf16* Kb = Kx + (size_t)bh*S_*DH_;
  const bf16* Vb = Vt + (size_t)bh*DH_*S_;

  bf16x8 qf[2];
  #pragma unroll
  for (int f=0; f<2; f++)
    qf[f] = *(const bf16x8*)&Qb[(size_t)(qb*64 + wave*16 + llo)*DH_ + f*32 + lhi*8];

  f32x4 oacc[4];
  #pragma unroll
  for (int f=0; f<4; f++) oacc[f] = (f32x4){0.f,0.f,0.f,0.f};
  float mrow[4], lrow[4];
  #pragma unroll
  for (int r=0;r<4;r++){ mrow[r] = -1e9f; lrow[r] = 0.f; }

  int KT = causal ? (qb+1) : (S_/64);

  for (int kb=0; kb<KT; kb++){
    const bf16* kt0 = Kb + (size_t)kb*64*DH_;
    #pragma unroll
    for (int s=0; s<2; s++){
      int e = s*2048 + tid*8;           // element index into 64x64 tile
      *(bf16x8*)&Ks[e] = *(const bf16x8*)&kt0[e];
      int vr = e >> 6, vc = e & 63;     // Vs[d=vr][k=vc..vc+7]
      *(bf16x8*)&Vs[e] = *(const bf16x8*)&Vb[(size_t)vr*S_ + (size_t)kb*64 + vc];
    }
    __syncthreads();

    // ---- QK^T
    f32x4 sc[4];
    #pragma unroll
    for (int f=0; f<4; f++){
      f32x4 z = (f32x4){0.f,0.f,0.f,0.f};
      #pragma unroll
      for (int ks=0; ks<2; ks++){
        bf16x8 kf = *(const bf16x8*)&Ks[(f*16+llo)*64 + ks*32 + lhi*8];
        z = __builtin_amdgcn_mfma_f32_16x16x32_bf16(qf[ks], kf, z, 0,0,0);
      }
      sc[f] = z;
    }
    #pragma unroll
    for (int f=0; f<4; f++)
      #pragma unroll
      for (int r=0;r<4;r++){
        float v = sc[f][r]*0.125f;
        if (causal && kb==KT-1){
          int gcol = kb*64 + f*16 + llo;
          int grow = qb*64 + wave*16 + lhi*4 + r;
          if (gcol > grow) v = -1e9f;
        }
        sc[f][r] = v;
      }

    // ---- online softmax
    float alpha[4], psum[4];
    #pragma unroll
    for (int r=0;r<4;r++){
      float vm = fmaxf(fmaxf(sc[0][r],sc[1][r]), fmaxf(sc[2][r],sc[3][r]));
      #pragma unroll
      for (int msk=1; msk<16; msk<<=1) vm = fmaxf(vm, __shfl_xor(vm, msk));
      float mn = fmaxf(mrow[r], vm);
      alpha[r] = __expf(mrow[r]-mn);
      mrow[r]  = mn;
      psum[r]  = 0.f;
    }
    #pragma unroll
    for (int f=0; f<4; f++)
      #pragma unroll
      for (int r=0;r<4;r++){
        float p = __expf(sc[f][r]-mrow[r]);
        psum[r] += p;
        Ps[wave][(lhi*4+r)*64 + f*16+llo] = (bf16)p;
      }
    #pragma unroll
    for (int r=0;r<4;r++){
      float s = psum[r];
      #pragma unroll
      for (int msk=1; msk<16; msk<<=1) s += __shfl_xor(s, msk);
      lrow[r] = lrow[r]*alpha[r] + s;
      #pragma unroll
      for (int f=0; f<4; f++) oacc[f][r] *= alpha[r];
    }
    __syncthreads();   // Ps visible before PV

    // ---- PV
    #pragma unroll
    for (int ks=0; ks<2; ks++){
      bf16x8 pf = *(const bf16x8*)&Ps[wave][llo*64 + ks*32 + lhi*8];
      #pragma unroll
      for (int f2=0; f2<4; f2++){
        bf16x8 vf = *(const bf16x8*)&Vs[(f2*16+llo)*64 + ks*32 + lhi*8];
        oacc[f2] = __builtin_amdgcn_mfma_f32_16x16x32_bf16(pf, vf, oacc[f2], 0,0,0);
      }
    }
    __syncthreads();   // protect Ks/Vs/Ps before next staging
  }

  int qg = qb*64 + wave*16;
  #pragma unroll
  for (int f2=0; f2<4; f2++)
    #pragma unroll
    for (int r=0;r<4;r++){
      int row = qg + lhi*4 + r;
      int dd  = f2*16 + llo;
      out[((size_t)(b*S_ + row))*D_ + h*DH_ + dd] = (bf16)(oacc[f2][r] / lrow[r]);
    }
}

// ------------------------------------------------------------------
extern "C" void kernel_launch(void* const* d_in, const int* in_sizes, int n_in,
                              void* d_out, int out_size, void* d_ws, size_t ws_size,
                              hipStream_t stream)
{
  (void)in_sizes; (void)n_in; (void)out_size; (void)ws_size;
  const float* enc = (const float*)d_in[0];
  const float* x2  = (const float*)d_in[1];
  const float* Wq1 = (const float*)d_in[2];  const float* bq1 = (const float*)d_in[3];
  const float* Wk1 = (const float*)d_in[4];  const float* bk1 = (const float*)d_in[5];
  const float* Wv1 = (const float*)d_in[6];  const float* bv1 = (const float*)d_in[7];
  const float* Wo1 = (const float*)d_in[8];  const float* bo1 = (const float*)d_in[9];
  const float* Wq2 = (const float*)d_in[10]; const float* bq2 = (const float*)d_in[11];
  const float* Wk2 = (const float*)d_in[12]; const float* bk2 = (const float*)d_in[13];
  const float* Wv2 = (const float*)d_in[14]; const float* bv2 = (const float*)d_in[15];
  const float* Wo2 = (const float*)d_in[16]; const float* bo2 = (const float*)d_in[17];
  const float* Wff1= (const float*)d_in[18]; const float* Wff2= (const float*)d_in[19];
  float* outp = (float*)d_out;

  char* ws = (char*)d_ws;
  size_t off = 0;
  auto alloc = [&](size_t bytes)->void*{ void* p = ws + off; off += (bytes+255)&~(size_t)255; return p; };
  bf16* Wt8   = (bf16*)alloc((size_t)8*512*512*2);     // 4 MiB
  bf16* Wff1t = (bf16*)alloc((size_t)DFF_*D_*2);       // 2 MiB
  bf16* Wff2t = (bf16*)alloc((size_t)D_*DFF_*2);       // 2 MiB
  float* bnsc = (float*)alloc(4*512*4);
  float* bnsh = (float*)alloc(4*512*4);
  size_t actB = (size_t)NTOK*D_*2;   // 12 MiB, 256-aligned
  bf16* X2b  = (bf16*)alloc(actB);   // bf16(x2)
  bf16* Abuf = (bf16*)alloc(actB);   // q
  bf16* Bbuf = (bf16*)alloc(actB);   // k
  bf16* Cbuf = (bf16*)alloc(actB);   // v -> attn_out
  bf16* Dv   = (bf16*)alloc(actB);   // v^T
  bf16* E1   = (bf16*)alloc(actB);   // xn -> x3
  bf16* E2   = (bf16*)alloc(actB);   // y = bn2(enc)
  bf16* Fbuf = Abuf;                 // ff1 [NTOK,DFF] overlays A,B,C,Dv (4*12 MiB), dead then

  bf16* Wtq1 = Wt8 + 0*262144;  bf16* Wtk1 = Wt8 + 1*262144;
  bf16* Wtv1 = Wt8 + 2*262144;  bf16* Wto1 = Wt8 + 3*262144;
  bf16* Wtq2 = Wt8 + 4*262144;  bf16* Wtk2 = Wt8 + 5*262144;
  bf16* Wtv2 = Wt8 + 6*262144;  bf16* Wto2 = Wt8 + 7*262144;

  Ptr8 p8;
  p8.s[0]=Wq1; p8.s[1]=Wk1; p8.s[2]=Wv1; p8.s[3]=Wo1;
  p8.s[4]=Wq2; p8.s[5]=Wk2; p8.s[6]=Wv2; p8.s[7]=Wo2;
  transpose_w8<<<dim3(8,8,8),256,0,stream>>>(p8, Wt8);
  transpose_rc<<<dim3(DFF_/64, D_/64),256,0,stream>>>(Wff1, Wff1t, D_, DFF_);
  transpose_rc<<<dim3(D_/64, DFF_/64),256,0,stream>>>(Wff2, Wff2t, DFF_, D_);

  Ptr16 p16;
  for (int i=0;i<16;i++) p16.p[i] = (const float*)d_in[20+i];
  bn_prep<<<4,512,0,stream>>>(p16, bnsc, bnsh);
  int cvtg = NTOK*D_/4/256;
  cvt_bn<<<cvtg,256,0,stream>>>(enc, bnsc+512, bnsh+512, E2);   // y = bn2(enc)
  cvt_bn<<<cvtg,256,0,stream>>>(x2, nullptr, nullptr, X2b);     // bf16(x2)

  auto gemm = [&](const bf16* Am, const bf16* W, const float* bias, const float* residf,
                  const float* sc, const float* sh, bf16* o, float* of, float* o2f,
                  int N, int K, int relu, int mode){
    gemm128<<<(NTOK/128)*(N/128), 256, 0, stream>>>(Am, W, bias, residf, sc, sh, o, of, o2f,
                                                    NTOK, N, K, relu, mode);
  };

  // ---- self-attention (causal) ----
  gemm(X2b, Wtq1, bq1, nullptr, nullptr, nullptr, Abuf, nullptr, nullptr, 512, 512, 0, 1);
  gemm(X2b, Wtk1, bk1, nullptr, nullptr, nullptr, Bbuf, nullptr, nullptr, 512, 512, 0, 1);
  gemm(X2b, Wtv1, bv1, nullptr, nullptr, nullptr, Cbuf, nullptr, nullptr, 512, 512, 0, 1);
  transpose_v<<<dim3(S_/64, B_*H_),256,0,stream>>>(Cbuf, Dv);
  attn<<<dim3(S_/64, B_*H_),256,0,stream>>>(Abuf, Bbuf, Dv, Cbuf, 1);
  // xn = bn1(attn@Wo1 + bo1 + x2)
  gemm(Cbuf, Wto1, bo1, x2, bnsc+0, bnsh+0, E1, nullptr, nullptr, 512, 512, 0, 0);

  // ---- cross-attention ----
  gemm(E1, Wtq2, bq2, nullptr, nullptr, nullptr, Abuf, nullptr, nullptr, 512, 512, 0, 1);
  gemm(E2, Wtk2, bk2, nullptr, nullptr, nullptr, Bbuf, nullptr, nullptr, 512, 512, 0, 1);
  gemm(E2, Wtv2, bv2, nullptr, nullptr, nullptr, Cbuf, nullptr, nullptr, 512, 512, 0, 1);
  transpose_v<<<dim3(S_/64, B_*H_),256,0,stream>>>(Cbuf, Dv);
  attn<<<dim3(S_/64, B_*H_),256,0,stream>>>(Abuf, Bbuf, Dv, Cbuf, 0);
  // cross_out(fp32) -> d_out; x3 = bn3(cross_out) -> E1
  gemm(Cbuf, Wto2, bo2, x2, bnsc+2*512, bnsh+2*512, E1, nullptr, outp, 512, 512, 0, 0);

  // ---- FFN ----
  gemm(E1, Wff1t, nullptr, nullptr, nullptr, nullptr, Fbuf, nullptr, nullptr, DFF_, 512, 1, 0);
  // out = bn4(ff1@Wff2 + cross_out)  — resid & final both in d_out (same-elem read-then-write)
  gemm(Fbuf, Wff2t, nullptr, outp, bnsc+3*512, bnsh+3*512, nullptr, outp, nullptr, 512, DFF_, 0, 0);
}

// Round 4
// 395.785 us; speedup vs baseline: 1.4083x; 1.4083x over previous
//
#include <hip/hip_runtime.h>
#include <cstdint>
#include <cstddef>

typedef __bf16 bf16;
typedef __bf16 bf16x8 __attribute__((ext_vector_type(8)));
typedef __bf16 bf16x4 __attribute__((ext_vector_type(4)));
typedef float  f32x4  __attribute__((ext_vector_type(4)));

#define B_   32
#define S_   384
#define D_   512
#define H_   8
#define DH_  64
#define DFF_ 2048
#define NTOK (B_*S_)

__device__ __forceinline__ void gload16(const void* g, void* l){
  __builtin_amdgcn_global_load_lds((__attribute__((address_space(1))) uint32_t*)(g),
                                   (__attribute__((address_space(3))) uint32_t*)(l), 16, 0, 0);
}

// ---------------- weight transpose: fp32 [K,N] -> bf16 [N,K] ----------------
struct Ptr8 { const float* s[8]; };
__global__ __launch_bounds__(256) void transpose_w8(Ptr8 ps, bf16* dst){
  __shared__ float t[64][65];
  int w = blockIdx.z;
  const float* src = ps.s[w];
  bf16* d = dst + (size_t)w*512*512;
  int tr = blockIdx.y*64, tc = blockIdx.x*64;
  for (int i=threadIdx.x; i<4096; i+=256){ int r=i>>6, c=i&63; t[r][c] = src[(size_t)(tr+r)*512 + tc+c]; }
  __syncthreads();
  for (int i=threadIdx.x; i<4096; i+=256){ int c=i>>6, r=i&63; d[(size_t)(tc+c)*512 + tr+r] = (bf16)t[r][c]; }
}

__global__ __launch_bounds__(256) void transpose_rc(const float* __restrict__ src, bf16* __restrict__ dst,
                                                    int R, int C){
  __shared__ float t[64][65];
  int tr = blockIdx.y*64, tc = blockIdx.x*64;
  for (int i=threadIdx.x; i<4096; i+=256){ int r=i>>6, c=i&63; t[r][c] = src[(size_t)(tr+r)*C + tc+c]; }
  __syncthreads();
  for (int i=threadIdx.x; i<4096; i+=256){ int c=i>>6, r=i&63; dst[(size_t)(tc+c)*R + tr+r] = (bf16)t[r][c]; }
}

// v [BH][S][64] bf16 -> vt [BH][64][S] bf16
__global__ __launch_bounds__(256) void transpose_v(const bf16* __restrict__ src, bf16* __restrict__ dst){
  __shared__ bf16 t[64][65];
  int bh = blockIdx.y; int sb = blockIdx.x*64;
  const bf16* s = src + (size_t)bh*S_*DH_;
  bf16* d = dst + (size_t)bh*DH_*S_;
  for (int i=threadIdx.x; i<4096; i+=256){ int r=i>>6, c=i&63; t[r][c] = s[(size_t)(sb+r)*DH_ + c]; }
  __syncthreads();
  for (int i=threadIdx.x; i<4096; i+=256){ int c=i>>6, r=i&63; d[(size_t)c*S_ + sb + r] = t[r][c]; }
}

// ---------------- BN scale/shift precompute: bn(x) = x*sc + sh ----------------
struct Ptr16 { const float* p[16]; };
__global__ __launch_bounds__(512) void bn_prep(Ptr16 q, float* sc, float* sh){
  int i = blockIdx.x;
  int n = threadIdx.x;
  float g = q.p[i*4+0][n];
  float b = q.p[i*4+1][n];
  float m = q.p[i*4+2][n];
  float v = q.p[i*4+3][n];
  float s = g * rsqrtf(v + 1e-3f);
  sc[i*512+n] = s;
  sh[i*512+n] = b - m*s;
}

// fp32 -> bf16, optional fused bn (sc!=null)
__global__ __launch_bounds__(256) void cvt_bn(const float* __restrict__ x, const float* __restrict__ sc,
                                              const float* __restrict__ sh, bf16* __restrict__ out){
  size_t e0 = ((size_t)blockIdx.x*256 + threadIdx.x)*4;
  int n0 = (int)(e0 & (D_-1));
  f32x4 xv = *(const f32x4*)(x + e0);
  bf16x4 ov;
  if (sc){
    #pragma unroll
    for (int j=0;j<4;j++) ov[j] = (bf16)(xv[j]*sc[n0+j] + sh[n0+j]);
  } else {
    #pragma unroll
    for (int j=0;j<4;j++) ov[j] = (bf16)xv[j];
  }
  *(bf16x4*)(out + e0) = ov;
}

// ---------------- 64x128 MFMA GEMM, BK=64, XOR-swizzled LDS, XCD-chunked ----------------
// A [M,K] bf16, Wt [N,K] bf16.
// mode 0: plain store (of fp32 if set, else o0 bf16), optional bias b0, resid, bn, relu, o2f pre-bn fp32.
// mode 1: per-512-col-segment head-split store: seg0->o0, seg1->o1b, seg2->o2b; bias b0/b1/b2 per seg.
__global__ __launch_bounds__(256,4) void gemm_bt(
    const bf16* __restrict__ A, const bf16* __restrict__ Wt,
    const float* __restrict__ b0, const float* __restrict__ b1, const float* __restrict__ b2,
    const float* __restrict__ residf,
    const float* __restrict__ bsc, const float* __restrict__ bsh,
    bf16* __restrict__ o0, bf16* __restrict__ o1b, bf16* __restrict__ o2b,
    float* __restrict__ of, float* __restrict__ o2f,
    int M, int N, int K, int relu, int mode)
{
  __shared__ bf16 As[64*64];    // 8 KB  [row][8 slots of 8 elems], slot XOR (row&7)
  __shared__ bf16 Bs[128*64];   // 16 KB
  int nwg = gridDim.x;
  int cpx = nwg >> 3;
  int bid = blockIdx.x;
  int swz = (bid & 7)*cpx + (bid >> 3);      // chunked XCD swizzle (nwg % 8 == 0)
  int tiles_n = N >> 7;
  int tm = swz / tiles_n, tn = swz - tm*tiles_n;

  int tid = threadIdx.x, wave = tid>>6, lane = tid&63;
  int lhi = lane>>4, llo = lane&15;
  int lrow = lane>>3, lcol = lane&7;
  int wr = wave>>1, wc = wave&1;

  f32x4 acc[2][4];
  #pragma unroll
  for (int i=0;i<2;i++)
    #pragma unroll
    for (int j=0;j<4;j++) acc[i][j] = (f32x4){0.f,0.f,0.f,0.f};

  const bf16* Abase = A  + (size_t)(tm*64)  * K;
  const bf16* Bbase = Wt + (size_t)(tn*128) * K;

  // staging row/col (pre-swizzled global source, linear LDS dest)
  int arow0 = wave*16, brow0 = wave*32;

  for (int kt=0; kt<K; kt+=64){
    #pragma unroll
    for (int q=0;q<2;q++){
      int r = arow0 + q*8 + lrow;
      int s = lcol ^ (r&7);
      gload16(Abase + (size_t)r*K + kt + s*8, (char*)As + wave*2048 + q*1024);
    }
    #pragma unroll
    for (int q=0;q<4;q++){
      int r = brow0 + q*8 + lrow;
      int s = lcol ^ (r&7);
      gload16(Bbase + (size_t)r*K + kt + s*8, (char*)Bs + wave*4096 + q*1024);
    }
    __syncthreads();
    #pragma unroll
    for (int ks=0; ks<2; ks++){
      bf16x8 af[2], bfr[4];
      #pragma unroll
      for (int i=0;i<2;i++){
        int row = wr*32 + i*16 + llo;
        int slot = (ks*4 + lhi) ^ (row&7);
        af[i] = *(const bf16x8*)&As[row*64 + slot*8];
      }
      #pragma unroll
      for (int j=0;j<4;j++){
        int row = wc*64 + j*16 + llo;
        int slot = (ks*4 + lhi) ^ (row&7);
        bfr[j] = *(const bf16x8*)&Bs[row*64 + slot*8];
      }
      #pragma unroll
      for (int i=0;i<2;i++)
        #pragma unroll
        for (int j=0;j<4;j++)
          acc[i][j] = __builtin_amdgcn_mfma_f32_16x16x32_bf16(af[i], bfr[j], acc[i][j], 0,0,0);
    }
    __syncthreads();
  }

  int m0 = tm*64 + wr*32, n0 = tn*128 + wc*64;
  #pragma unroll
  for (int i=0;i<2;i++){
    #pragma unroll
    for (int rr=0;rr<4;rr++){
      int gm = m0 + i*16 + lhi*4 + rr;
      #pragma unroll
      for (int j=0;j<4;j++){
        int gn = n0 + j*16 + llo;
        float v = acc[i][j][rr];
        if (b0){
          const float* bp = (gn < 512) ? b0 : ((gn < 1024) ? b1 : b2);
          v += bp[gn & 511];
        }
        if (residf) v += residf[(size_t)gm*N + gn];
        if (o2f)    o2f[(size_t)gm*N + gn] = v;
        if (bsc)    v = v*bsc[gn & 511] + bsh[gn & 511];
        if (relu)   v = fmaxf(v, 0.f);
        if (mode == 0){
          if (of) of[(size_t)gm*N + gn] = v;
          else    o0[(size_t)gm*N + gn] = (bf16)v;
        } else {
          int seg = gn >> 9;
          bf16* hp = (seg == 0) ? o0 : ((seg == 1) ? o1b : o2b);
          int cn = gn & 511;
          int h = cn >> 6, dd = cn & 63;
          int bb = gm / S_, ss = gm - bb*S_;
          hp[(((size_t)(bb*H_ + h))*S_ + ss)*DH_ + dd] = (bf16)v;
        }
      }
    }
  }
}

// ---------------- flash attention (conservative staging, full barriers)
// Q [BH,S,64], K [BH,S,64], Vt [BH,64,S] -> out merged [B,S,512]   (all bf16)
__global__ __launch_bounds__(256,2) void attn(
    const bf16* __restrict__ Q, const bf16* __restrict__ Kx,
    const bf16* __restrict__ Vt, bf16* __restrict__ out, int causal)
{
  __shared__ bf16 Ks[64*64];   // [key][d]
  __shared__ bf16 Vs[64*64];   // [d][key]
  __shared__ bf16 Ps[4][16*64];
  int qb = blockIdx.x, bh = blockIdx.y;
  int b = bh >> 3, h = bh & 7;
  int tid = threadIdx.x, wave = tid>>6, lane = tid&63;
  int lhi = lane>>4, llo = lane&15;
  const bf16* Qb = Q  + (size_t)bh*S_*DH_;
  const bf16* Kb = Kx + (size_t)bh*S_*DH_;
  const bf16* Vb = Vt + (size_t)bh*DH_*S_;

  bf16x8 qf[2];
  #pragma unroll
  for (int f=0; f<2; f++)
    qf[f] = *(const bf16x8*)&Qb[(size_t)(qb*64 + wave*16 + llo)*DH_ + f*32 + lhi*8];

  f32x4 oacc[4];
  #pragma unroll
  for (int f=0; f<4; f++) oacc[f] = (f32x4){0.f,0.f,0.f,0.f};
  float mrow[4], lrow4[4];
  #pragma unroll
  for (int r=0;r<4;r++){ mrow[r] = -1e9f; lrow4[r] = 0.f; }

  int KT = causal ? (qb+1) : (S_/64);

  for (int kb=0; kb<KT; kb++){
    const bf16* kt0 = Kb + (size_t)kb*64*DH_;
    #pragma unroll
    for (int s=0; s<2; s++){
      int e = s*2048 + tid*8;
      *(bf16x8*)&Ks[e] = *(const bf16x8*)&kt0[e];
      int vr = e >> 6, vc = e & 63;
      *(bf16x8*)&Vs[e] = *(const bf16x8*)&Vb[(size_t)vr*S_ + (size_t)kb*64 + vc];
    }
    __syncthreads();

    f32x4 sc[4];
    #pragma unroll
    for (int f=0; f<4; f++){
      f32x4 z = (f32x4){0.f,0.f,0.f,0.f};
      #pragma unroll
      for (int ks=0; ks<2; ks++){
        bf16x8 kf = *(const bf16x8*)&Ks[(f*16+llo)*64 + ks*32 + lhi*8];
        z = __builtin_amdgcn_mfma_f32_16x16x32_bf16(qf[ks], kf, z, 0,0,0);
      }
      sc[f] = z;
    }
    #pragma unroll
    for (int f=0; f<4; f++)
      #pragma unroll
      for (int r=0;r<4;r++){
        float v = sc[f][r]*0.125f;
        if (causal && kb==KT-1){
          int gcol = kb*64 + f*16 + llo;
          int grow = qb*64 + wave*16 + lhi*4 + r;
          if (gcol > grow) v = -1e9f;
        }
        sc[f][r] = v;
      }

    float alpha[4], psum[4];
    #pragma unroll
    for (int r=0;r<4;r++){
      float vm = fmaxf(fmaxf(sc[0][r],sc[1][r]), fmaxf(sc[2][r],sc[3][r]));
      #pragma unroll
      for (int msk=1; msk<16; msk<<=1) vm = fmaxf(vm, __shfl_xor(vm, msk));
      float mn = fmaxf(mrow[r], vm);
      alpha[r] = __expf(mrow[r]-mn);
      mrow[r]  = mn;
      psum[r]  = 0.f;
    }
    #pragma unroll
    for (int f=0; f<4; f++)
      #pragma unroll
      for (int r=0;r<4;r++){
        float p = __expf(sc[f][r]-mrow[r]);
        psum[r] += p;
        Ps[wave][(lhi*4+r)*64 + f*16+llo] = (bf16)p;
      }
    #pragma unroll
    for (int r=0;r<4;r++){
      float s = psum[r];
      #pragma unroll
      for (int msk=1; msk<16; msk<<=1) s += __shfl_xor(s, msk);
      lrow4[r] = lrow4[r]*alpha[r] + s;
      #pragma unroll
      for (int f=0; f<4; f++) oacc[f][r] *= alpha[r];
    }
    __syncthreads();

    #pragma unroll
    for (int ks=0; ks<2; ks++){
      bf16x8 pf = *(const bf16x8*)&Ps[wave][llo*64 + ks*32 + lhi*8];
      #pragma unroll
      for (int f2=0; f2<4; f2++){
        bf16x8 vf = *(const bf16x8*)&Vs[(f2*16+llo)*64 + ks*32 + lhi*8];
        oacc[f2] = __builtin_amdgcn_mfma_f32_16x16x32_bf16(pf, vf, oacc[f2], 0,0,0);
      }
    }
    __syncthreads();
  }

  int qg = qb*64 + wave*16;
  #pragma unroll
  for (int f2=0; f2<4; f2++)
    #pragma unroll
    for (int r=0;r<4;r++){
      int row = qg + lhi*4 + r;
      int dd  = f2*16 + llo;
      out[((size_t)(b*S_ + row))*D_ + h*DH_ + dd] = (bf16)(oacc[f2][r] / lrow4[r]);
    }
}

// ------------------------------------------------------------------
extern "C" void kernel_launch(void* const* d_in, const int* in_sizes, int n_in,
                              void* d_out, int out_size, void* d_ws, size_t ws_size,
                              hipStream_t stream)
{
  (void)in_sizes; (void)n_in; (void)out_size; (void)ws_size;
  const float* enc = (const float*)d_in[0];
  const float* x2  = (const float*)d_in[1];
  const float* Wq1 = (const float*)d_in[2];  const float* bq1 = (const float*)d_in[3];
  const float* Wk1 = (const float*)d_in[4];  const float* bk1 = (const float*)d_in[5];
  const float* Wv1 = (const float*)d_in[6];  const float* bv1 = (const float*)d_in[7];
  const float* Wo1 = (const float*)d_in[8];  const float* bo1 = (const float*)d_in[9];
  const float* Wq2 = (const float*)d_in[10]; const float* bq2 = (const float*)d_in[11];
  const float* Wk2 = (const float*)d_in[12]; const float* bk2 = (const float*)d_in[13];
  const float* Wv2 = (const float*)d_in[14]; const float* bv2 = (const float*)d_in[15];
  const float* Wo2 = (const float*)d_in[16]; const float* bo2 = (const float*)d_in[17];
  const float* Wff1= (const float*)d_in[18]; const float* Wff2= (const float*)d_in[19];
  float* outp = (float*)d_out;

  char* ws = (char*)d_ws;
  size_t off = 0;
  auto alloc = [&](size_t bytes)->void*{ void* p = ws + off; off += (bytes+255)&~(size_t)255; return p; };
  bf16* Wt8   = (bf16*)alloc((size_t)8*512*512*2);     // q1,k1,v1,o1,q2,k2,v2,o2  [N,K] rows contiguous
  bf16* Wff1t = (bf16*)alloc((size_t)DFF_*D_*2);
  bf16* Wff2t = (bf16*)alloc((size_t)D_*DFF_*2);
  float* bnsc = (float*)alloc(4*512*4);
  float* bnsh = (float*)alloc(4*512*4);
  size_t actB = (size_t)NTOK*D_*2;
  bf16* X2b  = (bf16*)alloc(actB);   // bf16(x2)
  bf16* Abuf = (bf16*)alloc(actB);   // q (head-split)
  bf16* Bbuf = (bf16*)alloc(actB);   // k (head-split)
  bf16* Cbuf = (bf16*)alloc(actB);   // v (head-split) -> attn_out (merged)
  bf16* Dv   = (bf16*)alloc(actB);   // v^T
  bf16* E1   = (bf16*)alloc(actB);   // xn -> x3
  bf16* E2   = (bf16*)alloc(actB);   // y = bn2(enc)
  bf16* Fbuf = Abuf;                 // ff1 [NTOK,DFF] overlays Abuf..Dv (48 MiB), dead by then

  bf16* Wtq1 = Wt8 + 0*262144;                          // [1536,512] = q1|k1|v1
  bf16* Wto1 = Wt8 + 3*262144;
  bf16* Wtq2 = Wt8 + 4*262144;
  bf16* Wtk2 = Wt8 + 5*262144;                          // [1024,512] = k2|v2
  bf16* Wto2 = Wt8 + 7*262144;

  Ptr8 p8;
  p8.s[0]=Wq1; p8.s[1]=Wk1; p8.s[2]=Wv1; p8.s[3]=Wo1;
  p8.s[4]=Wq2; p8.s[5]=Wk2; p8.s[6]=Wv2; p8.s[7]=Wo2;
  transpose_w8<<<dim3(8,8,8),256,0,stream>>>(p8, Wt8);
  transpose_rc<<<dim3(DFF_/64, D_/64),256,0,stream>>>(Wff1, Wff1t, D_, DFF_);
  transpose_rc<<<dim3(D_/64, DFF_/64),256,0,stream>>>(Wff2, Wff2t, DFF_, D_);

  Ptr16 p16;
  for (int i=0;i<16;i++) p16.p[i] = (const float*)d_in[20+i];
  bn_prep<<<4,512,0,stream>>>(p16, bnsc, bnsh);
  int cvtg = NTOK*D_/4/256;
  cvt_bn<<<cvtg,256,0,stream>>>(enc, bnsc+512, bnsh+512, E2);   // y = bn2(enc)
  cvt_bn<<<cvtg,256,0,stream>>>(x2, nullptr, nullptr, X2b);     // bf16(x2)

  auto gemm = [&](const bf16* Am, const bf16* W,
                  const float* bb0, const float* bb1, const float* bb2,
                  const float* residf, const float* sc, const float* sh,
                  bf16* oo0, bf16* oo1, bf16* oo2, float* of, float* o2f,
                  int N, int K, int relu, int mode){
    gemm_bt<<<(NTOK/64)*(N/128), 256, 0, stream>>>(Am, W, bb0, bb1, bb2, residf, sc, sh,
                                                   oo0, oo1, oo2, of, o2f, NTOK, N, K, relu, mode);
  };

  // ---- self-attention (causal): fused QKV projection ----
  gemm(X2b, Wtq1, bq1, bk1, bv1, nullptr, nullptr, nullptr,
       Abuf, Bbuf, Cbuf, nullptr, nullptr, 1536, 512, 0, 1);
  transpose_v<<<dim3(S_/64, B_*H_),256,0,stream>>>(Cbuf, Dv);
  attn<<<dim3(S_/64, B_*H_),256,0,stream>>>(Abuf, Bbuf, Dv, Cbuf, 1);
  // xn = bn1(attn@Wo1 + bo1 + x2) -> E1
  gemm(Cbuf, Wto1, bo1, nullptr, nullptr, x2, bnsc+0, bnsh+0,
       E1, nullptr, nullptr, nullptr, nullptr, 512, 512, 0, 0);

  // ---- cross-attention: Q from E1; fused KV from E2 ----
  gemm(E1, Wtq2, bq2, nullptr, nullptr, nullptr, nullptr, nullptr,
       Abuf, nullptr, nullptr, nullptr, nullptr, 512, 512, 0, 1);
  gemm(E2, Wtk2, bk2, bv2, nullptr, nullptr, nullptr, nullptr,
       Bbuf, Cbuf, nullptr, nullptr, nullptr, 1024, 512, 0, 1);
  transpose_v<<<dim3(S_/64, B_*H_),256,0,stream>>>(Cbuf, Dv);
  attn<<<dim3(S_/64, B_*H_),256,0,stream>>>(Abuf, Bbuf, Dv, Cbuf, 0);
  // cross_out(fp32) -> d_out; x3 = bn3(cross_out) -> E1
  gemm(Cbuf, Wto2, bo2, nullptr, nullptr, x2, bnsc+2*512, bnsh+2*512,
       E1, nullptr, nullptr, nullptr, outp, 512, 512, 0, 0);

  // ---- FFN ----
  gemm(E1, Wff1t, nullptr, nullptr, nullptr, nullptr, nullptr, nullptr,
       Fbuf, nullptr, nullptr, nullptr, nullptr, DFF_, 512, 1, 0);
  // out = bn4(ff1@Wff2 + cross_out)
  gemm(Fbuf, Wff2t, nullptr, nullptr, nullptr, outp, bnsc+3*512, bnsh+3*512,
       nullptr, nullptr, nullptr, outp, nullptr, 512, DFF_, 0, 0);
}

// Round 5
// 366.405 us; speedup vs baseline: 1.5213x; 1.0802x over previous
//
#include <hip/hip_runtime.h>
#include <cstdint>
#include <cstddef>

typedef __bf16 bf16;
typedef __bf16 bf16x8 __attribute__((ext_vector_type(8)));
typedef __bf16 bf16x4 __attribute__((ext_vector_type(4)));
typedef float  f32x4  __attribute__((ext_vector_type(4)));

#define B_   32
#define S_   384
#define D_   512
#define H_   8
#define DH_  64
#define DFF_ 2048
#define NTOK (B_*S_)

__device__ __forceinline__ void gload16(const void* g, void* l){
  __builtin_amdgcn_global_load_lds((__attribute__((address_space(1))) uint32_t*)(g),
                                   (__attribute__((address_space(3))) uint32_t*)(l), 16, 0, 0);
}

// ---------------- weight transpose: fp32 [K,N] -> bf16 [N,K] ----------------
struct Ptr8 { const float* s[8]; };
__global__ __launch_bounds__(256) void transpose_w8(Ptr8 ps, bf16* dst){
  __shared__ float t[64][65];
  int w = blockIdx.z;
  const float* src = ps.s[w];
  bf16* d = dst + (size_t)w*512*512;
  int tr = blockIdx.y*64, tc = blockIdx.x*64;
  for (int i=threadIdx.x; i<4096; i+=256){ int r=i>>6, c=i&63; t[r][c] = src[(size_t)(tr+r)*512 + tc+c]; }
  __syncthreads();
  for (int i=threadIdx.x; i<4096; i+=256){ int c=i>>6, r=i&63; d[(size_t)(tc+c)*512 + tr+r] = (bf16)t[r][c]; }
}

__global__ __launch_bounds__(256) void transpose_rc(const float* __restrict__ src, bf16* __restrict__ dst,
                                                    int R, int C){
  __shared__ float t[64][65];
  int tr = blockIdx.y*64, tc = blockIdx.x*64;
  for (int i=threadIdx.x; i<4096; i+=256){ int r=i>>6, c=i&63; t[r][c] = src[(size_t)(tr+r)*C + tc+c]; }
  __syncthreads();
  for (int i=threadIdx.x; i<4096; i+=256){ int c=i>>6, r=i&63; dst[(size_t)(tc+c)*R + tr+r] = (bf16)t[r][c]; }
}

// v [BH][S][64] bf16 -> vt [BH][64][S] bf16
__global__ __launch_bounds__(256) void transpose_v(const bf16* __restrict__ src, bf16* __restrict__ dst){
  __shared__ bf16 t[64][65];
  int bh = blockIdx.y; int sb = blockIdx.x*64;
  const bf16* s = src + (size_t)bh*S_*DH_;
  bf16* d = dst + (size_t)bh*DH_*S_;
  for (int i=threadIdx.x; i<4096; i+=256){ int r=i>>6, c=i&63; t[r][c] = s[(size_t)(sb+r)*DH_ + c]; }
  __syncthreads();
  for (int i=threadIdx.x; i<4096; i+=256){ int c=i>>6, r=i&63; d[(size_t)c*S_ + sb + r] = t[r][c]; }
}

// ---------------- BN scale/shift precompute: bn(x) = x*sc + sh ----------------
struct Ptr16 { const float* p[16]; };
__global__ __launch_bounds__(512) void bn_prep(Ptr16 q, float* sc, float* sh){
  int i = blockIdx.x;
  int n = threadIdx.x;
  float g = q.p[i*4+0][n];
  float b = q.p[i*4+1][n];
  float m = q.p[i*4+2][n];
  float v = q.p[i*4+3][n];
  float s = g * rsqrtf(v + 1e-3f);
  sc[i*512+n] = s;
  sh[i*512+n] = b - m*s;
}

// fp32 -> bf16, optional fused bn (sc!=null)
__global__ __launch_bounds__(256) void cvt_bn(const float* __restrict__ x, const float* __restrict__ sc,
                                              const float* __restrict__ sh, bf16* __restrict__ out){
  size_t e0 = ((size_t)blockIdx.x*256 + threadIdx.x)*4;
  int n0 = (int)(e0 & (D_-1));
  f32x4 xv = *(const f32x4*)(x + e0);
  bf16x4 ov;
  if (sc){
    #pragma unroll
    for (int j=0;j<4;j++) ov[j] = (bf16)(xv[j]*sc[n0+j] + sh[n0+j]);
  } else {
    #pragma unroll
    for (int j=0;j<4;j++) ov[j] = (bf16)xv[j];
  }
  *(bf16x4*)(out + e0) = ov;
}

// ---------------- 64x128 MFMA GEMM, BK=64, XOR-swizzled LDS, XCD-chunked ----------------
__global__ __launch_bounds__(256,4) void gemm_bt(
    const bf16* __restrict__ A, const bf16* __restrict__ Wt,
    const float* __restrict__ b0, const float* __restrict__ b1, const float* __restrict__ b2,
    const float* __restrict__ residf,
    const float* __restrict__ bsc, const float* __restrict__ bsh,
    bf16* __restrict__ o0, bf16* __restrict__ o1b, bf16* __restrict__ o2b,
    float* __restrict__ of, float* __restrict__ o2f,
    int M, int N, int K, int relu, int mode)
{
  __shared__ bf16 As[64*64];
  __shared__ bf16 Bs[128*64];
  int nwg = gridDim.x;
  int cpx = nwg >> 3;
  int bid = blockIdx.x;
  int swz = (bid & 7)*cpx + (bid >> 3);
  int tiles_n = N >> 7;
  int tm = swz / tiles_n, tn = swz - tm*tiles_n;

  int tid = threadIdx.x, wave = tid>>6, lane = tid&63;
  int lhi = lane>>4, llo = lane&15;
  int lrow = lane>>3, lcol = lane&7;
  int wr = wave>>1, wc = wave&1;

  f32x4 acc[2][4];
  #pragma unroll
  for (int i=0;i<2;i++)
    #pragma unroll
    for (int j=0;j<4;j++) acc[i][j] = (f32x4){0.f,0.f,0.f,0.f};

  const bf16* Abase = A  + (size_t)(tm*64)  * K;
  const bf16* Bbase = Wt + (size_t)(tn*128) * K;

  int arow0 = wave*16, brow0 = wave*32;

  for (int kt=0; kt<K; kt+=64){
    #pragma unroll
    for (int q=0;q<2;q++){
      int r = arow0 + q*8 + lrow;
      int s = lcol ^ (r&7);
      gload16(Abase + (size_t)r*K + kt + s*8, (char*)As + wave*2048 + q*1024);
    }
    #pragma unroll
    for (int q=0;q<4;q++){
      int r = brow0 + q*8 + lrow;
      int s = lcol ^ (r&7);
      gload16(Bbase + (size_t)r*K + kt + s*8, (char*)Bs + wave*4096 + q*1024);
    }
    __syncthreads();
    #pragma unroll
    for (int ks=0; ks<2; ks++){
      bf16x8 af[2], bfr[4];
      #pragma unroll
      for (int i=0;i<2;i++){
        int row = wr*32 + i*16 + llo;
        int slot = (ks*4 + lhi) ^ (row&7);
        af[i] = *(const bf16x8*)&As[row*64 + slot*8];
      }
      #pragma unroll
      for (int j=0;j<4;j++){
        int row = wc*64 + j*16 + llo;
        int slot = (ks*4 + lhi) ^ (row&7);
        bfr[j] = *(const bf16x8*)&Bs[row*64 + slot*8];
      }
      #pragma unroll
      for (int i=0;i<2;i++)
        #pragma unroll
        for (int j=0;j<4;j++)
          acc[i][j] = __builtin_amdgcn_mfma_f32_16x16x32_bf16(af[i], bfr[j], acc[i][j], 0,0,0);
    }
    __syncthreads();
  }

  int m0 = tm*64 + wr*32, n0 = tn*128 + wc*64;
  #pragma unroll
  for (int i=0;i<2;i++){
    #pragma unroll
    for (int rr=0;rr<4;rr++){
      int gm = m0 + i*16 + lhi*4 + rr;
      #pragma unroll
      for (int j=0;j<4;j++){
        int gn = n0 + j*16 + llo;
        float v = acc[i][j][rr];
        if (b0){
          const float* bp = (gn < 512) ? b0 : ((gn < 1024) ? b1 : b2);
          v += bp[gn & 511];
        }
        if (residf) v += residf[(size_t)gm*N + gn];
        if (o2f)    o2f[(size_t)gm*N + gn] = v;
        if (bsc)    v = v*bsc[gn & 511] + bsh[gn & 511];
        if (relu)   v = fmaxf(v, 0.f);
        if (mode == 0){
          if (of) of[(size_t)gm*N + gn] = v;
          else    o0[(size_t)gm*N + gn] = (bf16)v;
        } else {
          int seg = gn >> 9;
          bf16* hp = (seg == 0) ? o0 : ((seg == 1) ? o1b : o2b);
          int cn = gn & 511;
          int h = cn >> 6, dd = cn & 63;
          int bb = gm / S_, ss = gm - bb*S_;
          hp[(((size_t)(bb*H_ + h))*S_ + ss)*DH_ + dd] = (bf16)v;
        }
      }
    }
  }
}

// ---------------- flash attention v2: XOR-swizzled LDS, T14 split-stage,
// wave-private Ps (no barrier), XCD-affinity block map.
// Q [BH,S,64], K [BH,S,64], Vt [BH,64,S] -> out merged [B,S,512]  (all bf16)
__global__ __launch_bounds__(256,4) void attn(
    const bf16* __restrict__ Q, const bf16* __restrict__ Kx,
    const bf16* __restrict__ Vt, bf16* __restrict__ out, int causal)
{
  __shared__ bf16 Ks[64*64];   // logical [key][d], slot XOR (row&7)
  __shared__ bf16 Vs[64*64];   // logical [d][key], slot XOR (row&7)
  __shared__ bf16 Ps[4][16*64];// per-wave, logical [qrow][key], slot XOR (row&7)
  int bid = blockIdx.x;
  int bh = bid & 255;          // bh%8 == bid%8 -> all q-blocks of a head on one XCD
  int qb = bid >> 8;
  int b = bh >> 3, h = bh & 7;
  int tid = threadIdx.x, wave = tid>>6, lane = tid&63;
  int lhi = lane>>4, llo = lane&15;
  int l7 = llo & 7;
  const bf16* Qb = Q  + (size_t)bh*S_*DH_;
  const bf16* Kb = Kx + (size_t)bh*S_*DH_;
  const bf16* Vb = Vt + (size_t)bh*DH_*S_;

  bf16x8 qf[2];
  #pragma unroll
  for (int f=0; f<2; f++)
    qf[f] = *(const bf16x8*)&Qb[(size_t)(qb*64 + wave*16 + llo)*DH_ + f*32 + lhi*8];

  f32x4 oacc[4];
  #pragma unroll
  for (int f=0; f<4; f++) oacc[f] = (f32x4){0.f,0.f,0.f,0.f};
  float mrow[4], lrow4[4];
  #pragma unroll
  for (int r=0;r<4;r++){ mrow[r] = -1e9f; lrow4[r] = 0.f; }

  int KT = causal ? (qb+1) : (S_/64);

  int srow0 = tid>>3, sslot = tid&7;       // staging: rows srow0, srow0+32
  bf16x8 kreg[2], vreg[2];

  // issue global loads for tile kb into regs
  auto issue = [&](int kb){
    const bf16* kt0 = Kb + (size_t)kb*64*DH_;
    #pragma unroll
    for (int s=0;s<2;s++){
      int row = s*32 + srow0;
      kreg[s] = *(const bf16x8*)&kt0[(size_t)row*64 + sslot*8];
      vreg[s] = *(const bf16x8*)&Vb[(size_t)row*S_ + (size_t)kb*64 + sslot*8];
    }
  };
  issue(0);

  for (int kb=0; kb<KT; kb++){
    // commit staged regs to swizzled LDS
    #pragma unroll
    for (int s=0;s<2;s++){
      int row = s*32 + srow0;
      int sl = sslot ^ (row&7);
      *(bf16x8*)&Ks[row*64 + sl*8] = kreg[s];
      *(bf16x8*)&Vs[row*64 + sl*8] = vreg[s];
    }
    __syncthreads();

    // ---- QK^T (swizzled Ks reads, conflict-free)
    f32x4 sc[4];
    #pragma unroll
    for (int f=0; f<4; f++){
      f32x4 z = (f32x4){0.f,0.f,0.f,0.f};
      #pragma unroll
      for (int ks=0; ks<2; ks++){
        int row = f*16 + llo;
        int slot = (ks*4 + lhi) ^ (row&7);
        bf16x8 kf = *(const bf16x8*)&Ks[row*64 + slot*8];
        z = __builtin_amdgcn_mfma_f32_16x16x32_bf16(qf[ks], kf, z, 0,0,0);
      }
      sc[f] = z;
    }
    #pragma unroll
    for (int f=0; f<4; f++)
      #pragma unroll
      for (int r=0;r<4;r++){
        float v = sc[f][r]*0.125f;
        if (causal && kb==KT-1){
          int gcol = kb*64 + f*16 + llo;
          int grow = qb*64 + wave*16 + lhi*4 + r;
          if (gcol > grow) v = -1e9f;
        }
        sc[f][r] = v;
      }

    // ---- online softmax
    float alpha[4], psum[4];
    #pragma unroll
    for (int r=0;r<4;r++){
      float vm = fmaxf(fmaxf(sc[0][r],sc[1][r]), fmaxf(sc[2][r],sc[3][r]));
      #pragma unroll
      for (int msk=1; msk<16; msk<<=1) vm = fmaxf(vm, __shfl_xor(vm, msk));
      float mn = fmaxf(mrow[r], vm);
      alpha[r] = __expf(mrow[r]-mn);
      mrow[r]  = mn;
      psum[r]  = 0.f;
    }
    #pragma unroll
    for (int f=0; f<4; f++)
      #pragma unroll
      for (int r=0;r<4;r++){
        float p = __expf(sc[f][r]-mrow[r]);
        psum[r] += p;
        int row = lhi*4 + r;
        int slot = (f*2 + (llo>>3)) ^ (row&7);
        Ps[wave][row*64 + slot*8 + l7] = (bf16)p;
      }
    #pragma unroll
    for (int r=0;r<4;r++){
      float s = psum[r];
      #pragma unroll
      for (int msk=1; msk<16; msk<<=1) s += __shfl_xor(s, msk);
      lrow4[r] = lrow4[r]*alpha[r] + s;
      #pragma unroll
      for (int f=0; f<4; f++) oacc[f][r] *= alpha[r];
    }

    // T14: issue next tile's global loads; HBM latency hides under PV
    if (kb+1 < KT) issue(kb+1);

    // Ps is wave-private: LDS RAW needs only lgkmcnt(0) (+ sched fence), no barrier
    asm volatile("s_waitcnt lgkmcnt(0)" ::: "memory");
    __builtin_amdgcn_sched_barrier(0);

    // ---- PV (swizzled Ps/Vs reads)
    #pragma unroll
    for (int ks=0; ks<2; ks++){
      int pslot = (ks*4 + lhi) ^ l7;
      bf16x8 pf = *(const bf16x8*)&Ps[wave][llo*64 + pslot*8];
      #pragma unroll
      for (int f2=0; f2<4; f2++){
        int row = f2*16 + llo;
        int slot = (ks*4 + lhi) ^ (row&7);
        bf16x8 vf = *(const bf16x8*)&Vs[row*64 + slot*8];
        oacc[f2] = __builtin_amdgcn_mfma_f32_16x16x32_bf16(pf, vf, oacc[f2], 0,0,0);
      }
    }
    __syncthreads();   // protect Ks/Vs before next commit
  }

  int qg = qb*64 + wave*16;
  #pragma unroll
  for (int f2=0; f2<4; f2++)
    #pragma unroll
    for (int r=0;r<4;r++){
      int row = qg + lhi*4 + r;
      int dd  = f2*16 + llo;
      out[((size_t)(b*S_ + row))*D_ + h*DH_ + dd] = (bf16)(oacc[f2][r] / lrow4[r]);
    }
}

// ------------------------------------------------------------------
extern "C" void kernel_launch(void* const* d_in, const int* in_sizes, int n_in,
                              void* d_out, int out_size, void* d_ws, size_t ws_size,
                              hipStream_t stream)
{
  (void)in_sizes; (void)n_in; (void)out_size; (void)ws_size;
  const float* enc = (const float*)d_in[0];
  const float* x2  = (const float*)d_in[1];
  const float* Wq1 = (const float*)d_in[2];  const float* bq1 = (const float*)d_in[3];
  const float* Wk1 = (const float*)d_in[4];  const float* bk1 = (const float*)d_in[5];
  const float* Wv1 = (const float*)d_in[6];  const float* bv1 = (const float*)d_in[7];
  const float* Wo1 = (const float*)d_in[8];  const float* bo1 = (const float*)d_in[9];
  const float* Wq2 = (const float*)d_in[10]; const float* bq2 = (const float*)d_in[11];
  const float* Wk2 = (const float*)d_in[12]; const float* bk2 = (const float*)d_in[13];
  const float* Wv2 = (const float*)d_in[14]; const float* bv2 = (const float*)d_in[15];
  const float* Wo2 = (const float*)d_in[16]; const float* bo2 = (const float*)d_in[17];
  const float* Wff1= (const float*)d_in[18]; const float* Wff2= (const float*)d_in[19];
  float* outp = (float*)d_out;

  char* ws = (char*)d_ws;
  size_t off = 0;
  auto alloc = [&](size_t bytes)->void*{ void* p = ws + off; off += (bytes+255)&~(size_t)255; return p; };
  bf16* Wt8   = (bf16*)alloc((size_t)8*512*512*2);
  bf16* Wff1t = (bf16*)alloc((size_t)DFF_*D_*2);
  bf16* Wff2t = (bf16*)alloc((size_t)D_*DFF_*2);
  float* bnsc = (float*)alloc(4*512*4);
  float* bnsh = (float*)alloc(4*512*4);
  size_t actB = (size_t)NTOK*D_*2;
  bf16* X2b  = (bf16*)alloc(actB);
  bf16* Abuf = (bf16*)alloc(actB);
  bf16* Bbuf = (bf16*)alloc(actB);
  bf16* Cbuf = (bf16*)alloc(actB);
  bf16* Dv   = (bf16*)alloc(actB);
  bf16* E1   = (bf16*)alloc(actB);
  bf16* E2   = (bf16*)alloc(actB);
  bf16* Fbuf = Abuf;

  bf16* Wtq1 = Wt8 + 0*262144;   // [1536,512] = q1|k1|v1
  bf16* Wto1 = Wt8 + 3*262144;
  bf16* Wtq2 = Wt8 + 4*262144;
  bf16* Wtk2 = Wt8 + 5*262144;   // [1024,512] = k2|v2
  bf16* Wto2 = Wt8 + 7*262144;

  Ptr8 p8;
  p8.s[0]=Wq1; p8.s[1]=Wk1; p8.s[2]=Wv1; p8.s[3]=Wo1;
  p8.s[4]=Wq2; p8.s[5]=Wk2; p8.s[6]=Wv2; p8.s[7]=Wo2;
  transpose_w8<<<dim3(8,8,8),256,0,stream>>>(p8, Wt8);
  transpose_rc<<<dim3(DFF_/64, D_/64),256,0,stream>>>(Wff1, Wff1t, D_, DFF_);
  transpose_rc<<<dim3(D_/64, DFF_/64),256,0,stream>>>(Wff2, Wff2t, DFF_, D_);

  Ptr16 p16;
  for (int i=0;i<16;i++) p16.p[i] = (const float*)d_in[20+i];
  bn_prep<<<4,512,0,stream>>>(p16, bnsc, bnsh);
  int cvtg = NTOK*D_/4/256;
  cvt_bn<<<cvtg,256,0,stream>>>(enc, bnsc+512, bnsh+512, E2);
  cvt_bn<<<cvtg,256,0,stream>>>(x2, nullptr, nullptr, X2b);

  auto gemm = [&](const bf16* Am, const bf16* W,
                  const float* bb0, const float* bb1, const float* bb2,
                  const float* residf, const float* sc, const float* sh,
                  bf16* oo0, bf16* oo1, bf16* oo2, float* of, float* o2f,
                  int N, int K, int relu, int mode){
    gemm_bt<<<(NTOK/64)*(N/128), 256, 0, stream>>>(Am, W, bb0, bb1, bb2, residf, sc, sh,
                                                   oo0, oo1, oo2, of, o2f, NTOK, N, K, relu, mode);
  };

  // ---- self-attention (causal): fused QKV projection ----
  gemm(X2b, Wtq1, bq1, bk1, bv1, nullptr, nullptr, nullptr,
       Abuf, Bbuf, Cbuf, nullptr, nullptr, 1536, 512, 0, 1);
  transpose_v<<<dim3(S_/64, B_*H_),256,0,stream>>>(Cbuf, Dv);
  attn<<<(S_/64)*B_*H_, 256, 0, stream>>>(Abuf, Bbuf, Dv, Cbuf, 1);
  gemm(Cbuf, Wto1, bo1, nullptr, nullptr, x2, bnsc+0, bnsh+0,
       E1, nullptr, nullptr, nullptr, nullptr, 512, 512, 0, 0);

  // ---- cross-attention ----
  gemm(E1, Wtq2, bq2, nullptr, nullptr, nullptr, nullptr, nullptr,
       Abuf, nullptr, nullptr, nullptr, nullptr, 512, 512, 0, 1);
  gemm(E2, Wtk2, bk2, bv2, nullptr, nullptr, nullptr, nullptr,
       Bbuf, Cbuf, nullptr, nullptr, nullptr, 1024, 512, 0, 1);
  transpose_v<<<dim3(S_/64, B_*H_),256,0,stream>>>(Cbuf, Dv);
  attn<<<(S_/64)*B_*H_, 256, 0, stream>>>(Abuf, Bbuf, Dv, Cbuf, 0);
  gemm(Cbuf, Wto2, bo2, nullptr, nullptr, x2, bnsc+2*512, bnsh+2*512,
       E1, nullptr, nullptr, nullptr, outp, 512, 512, 0, 0);

  // ---- FFN ----
  gemm(E1, Wff1t, nullptr, nullptr, nullptr, nullptr, nullptr, nullptr,
       Fbuf, nullptr, nullptr, nullptr, nullptr, DFF_, 512, 1, 0);
  gemm(Fbuf, Wff2t, nullptr, nullptr, nullptr, outp, bnsc+3*512, bnsh+3*512,
       nullptr, nullptr, nullptr, outp, nullptr, 512, DFF_, 0, 0);
}

// Round 6
// 332.275 us; speedup vs baseline: 1.6775x; 1.1027x over previous
//
#include <hip/hip_runtime.h>
#include <cstdint>
#include <cstddef>

typedef __bf16 bf16;
typedef __bf16 bf16x8 __attribute__((ext_vector_type(8)));
typedef __bf16 bf16x4 __attribute__((ext_vector_type(4)));
typedef float  f32x4  __attribute__((ext_vector_type(4)));

#define B_   32
#define S_   384
#define D_   512
#define H_   8
#define DH_  64
#define DFF_ 2048
#define NTOK (B_*S_)

__device__ __forceinline__ void gload16(const void* g, void* l){
  __builtin_amdgcn_global_load_lds((__attribute__((address_space(1))) uint32_t*)(g),
                                   (__attribute__((address_space(3))) uint32_t*)(l), 16, 0, 0);
}

// ---------------- weight transpose: fp32 [K,N] -> bf16 [N,K] ----------------
struct Ptr8 { const float* s[8]; };
__global__ __launch_bounds__(256) void transpose_w8(Ptr8 ps, bf16* dst){
  __shared__ float t[64][65];
  int w = blockIdx.z;
  const float* src = ps.s[w];
  bf16* d = dst + (size_t)w*512*512;
  int tr = blockIdx.y*64, tc = blockIdx.x*64;
  for (int i=threadIdx.x; i<4096; i+=256){ int r=i>>6, c=i&63; t[r][c] = src[(size_t)(tr+r)*512 + tc+c]; }
  __syncthreads();
  for (int i=threadIdx.x; i<4096; i+=256){ int c=i>>6, r=i&63; d[(size_t)(tc+c)*512 + tr+r] = (bf16)t[r][c]; }
}

__global__ __launch_bounds__(256) void transpose_rc(const float* __restrict__ src, bf16* __restrict__ dst,
                                                    int R, int C){
  __shared__ float t[64][65];
  int tr = blockIdx.y*64, tc = blockIdx.x*64;
  for (int i=threadIdx.x; i<4096; i+=256){ int r=i>>6, c=i&63; t[r][c] = src[(size_t)(tr+r)*C + tc+c]; }
  __syncthreads();
  for (int i=threadIdx.x; i<4096; i+=256){ int c=i>>6, r=i&63; dst[(size_t)(tc+c)*R + tr+r] = (bf16)t[r][c]; }
}

// ---------------- BN scale/shift precompute: bn(x) = x*sc + sh ----------------
struct Ptr16 { const float* p[16]; };
__global__ __launch_bounds__(512) void bn_prep(Ptr16 q, float* sc, float* sh){
  int i = blockIdx.x;
  int n = threadIdx.x;
  float g = q.p[i*4+0][n];
  float b = q.p[i*4+1][n];
  float m = q.p[i*4+2][n];
  float v = q.p[i*4+3][n];
  float s = g * rsqrtf(v + 1e-3f);
  sc[i*512+n] = s;
  sh[i*512+n] = b - m*s;
}

// fused: y=0 -> bn2(enc) -> E2 ; y=1 -> bf16(x2) -> X2b
__global__ __launch_bounds__(256) void cvt2(const float* __restrict__ enc, const float* __restrict__ x2,
                                            const float* __restrict__ sc, const float* __restrict__ sh,
                                            bf16* __restrict__ E2, bf16* __restrict__ X2b){
  size_t e0 = ((size_t)blockIdx.x*256 + threadIdx.x)*4;
  if (blockIdx.y == 0){
    int n0 = (int)(e0 & (D_-1));
    f32x4 xv = *(const f32x4*)(enc + e0);
    bf16x4 ov;
    #pragma unroll
    for (int j=0;j<4;j++) ov[j] = (bf16)(xv[j]*sc[n0+j] + sh[n0+j]);
    *(bf16x4*)(E2 + e0) = ov;
  } else {
    f32x4 xv = *(const f32x4*)(x2 + e0);
    bf16x4 ov;
    #pragma unroll
    for (int j=0;j<4;j++) ov[j] = (bf16)xv[j];
    *(bf16x4*)(X2b + e0) = ov;
  }
}

// ---------------- 64x128 MFMA GEMM, BK=64, 2-phase dbuf LDS, XOR-swizzle, XCD-chunked ----
// A [M,K] bf16, Wt [N,K] bf16.
// mode 0: out = of (fp32) if set else o0 (bf16); optional bias b0, residb (bf16), pre (bf16 pre-bn),
//         bn (bsc/bsh), relu.
// mode 1: per-512-col segment: seg==vseg -> transposed V store into vt [BH][64][S];
//         else head-split [B,H,S,dh] store: seg0->o0, seg1->o1b. bias b0/b1/b2 per segment.
__global__ __launch_bounds__(256,3) void gemm_bt(
    const bf16* __restrict__ A, const bf16* __restrict__ Wt,
    const float* __restrict__ b0, const float* __restrict__ b1, const float* __restrict__ b2,
    const bf16* __restrict__ residb,
    const float* __restrict__ bsc, const float* __restrict__ bsh,
    bf16* __restrict__ o0, bf16* __restrict__ o1b,
    bf16* __restrict__ vt, int vseg,
    float* __restrict__ of, bf16* __restrict__ pre,
    int M, int N, int K, int relu, int mode)
{
  __shared__ bf16 As[2][64*64];
  __shared__ bf16 Bs[2][128*64];
  int nwg = gridDim.x;
  int cpx = nwg >> 3;
  int bid = blockIdx.x;
  int swz = (bid & 7)*cpx + (bid >> 3);
  int tiles_n = N >> 7;
  int tm = swz / tiles_n, tn = swz - tm*tiles_n;

  int tid = threadIdx.x, wave = tid>>6, lane = tid&63;
  int lhi = lane>>4, llo = lane&15;
  int lrow = lane>>3, lcol = lane&7;
  int wr = wave>>1, wc = wave&1;

  f32x4 acc[2][4];
  #pragma unroll
  for (int i=0;i<2;i++)
    #pragma unroll
    for (int j=0;j<4;j++) acc[i][j] = (f32x4){0.f,0.f,0.f,0.f};

  const bf16* Abase = A  + (size_t)(tm*64)  * K;
  const bf16* Bbase = Wt + (size_t)(tn*128) * K;

  int arow0 = wave*16, brow0 = wave*32;

  auto STAGE = [&](int buf, int kt){
    #pragma unroll
    for (int q=0;q<2;q++){
      int r = arow0 + q*8 + lrow;
      int s = lcol ^ (r&7);
      gload16(Abase + (size_t)r*K + kt + s*8, (char*)&As[buf][0] + wave*2048 + q*1024);
    }
    #pragma unroll
    for (int q=0;q<4;q++){
      int r = brow0 + q*8 + lrow;
      int s = lcol ^ (r&7);
      gload16(Bbase + (size_t)r*K + kt + s*8, (char*)&Bs[buf][0] + wave*4096 + q*1024);
    }
  };

  STAGE(0, 0);
  __syncthreads();
  int nt = K >> 6;
  int cur = 0;
  for (int t=0; t<nt; ++t){
    if (t+1 < nt) STAGE(cur^1, (t+1)<<6);    // prefetch next tile; latency hides under MFMA
    #pragma unroll
    for (int ks=0; ks<2; ks++){
      bf16x8 af[2], bfr[4];
      #pragma unroll
      for (int i=0;i<2;i++){
        int row = wr*32 + i*16 + llo;
        int slot = (ks*4 + lhi) ^ (row&7);
        af[i] = *(const bf16x8*)&As[cur][row*64 + slot*8];
      }
      #pragma unroll
      for (int j=0;j<4;j++){
        int row = wc*64 + j*16 + llo;
        int slot = (ks*4 + lhi) ^ (row&7);
        bfr[j] = *(const bf16x8*)&Bs[cur][row*64 + slot*8];
      }
      #pragma unroll
      for (int i=0;i<2;i++)
        #pragma unroll
        for (int j=0;j<4;j++)
          acc[i][j] = __builtin_amdgcn_mfma_f32_16x16x32_bf16(af[i], bfr[j], acc[i][j], 0,0,0);
    }
    __syncthreads();   // drains prefetch vmcnt + protects cur for overwrite at t+2
    cur ^= 1;
  }

  int m0 = tm*64 + wr*32, n0 = tn*128 + wc*64;
  #pragma unroll
  for (int i=0;i<2;i++){
    #pragma unroll
    for (int j=0;j<4;j++){
      int gn = n0 + j*16 + llo;
      float vv[4];
      #pragma unroll
      for (int rr=0;rr<4;rr++){
        int gm = m0 + i*16 + lhi*4 + rr;
        float v = acc[i][j][rr];
        if (b0){
          const float* bp = (gn < 512) ? b0 : ((gn < 1024) ? b1 : b2);
          v += bp[gn & 511];
        }
        if (residb) v += (float)residb[(size_t)gm*N + gn];
        vv[rr] = v;
      }
      int gm0 = m0 + i*16 + lhi*4;
      if (mode == 1){
        int seg = gn >> 9, cn = gn & 511;
        int h = cn >> 6, dd = cn & 63;
        int bb = gm0 / S_, ss0 = gm0 - bb*S_;
        if (seg == vseg){
          bf16x4 v4;
          #pragma unroll
          for (int rr=0;rr<4;rr++) v4[rr] = (bf16)vv[rr];
          *(bf16x4*)&vt[((size_t)(bb*H_ + h)*DH_ + dd)*S_ + ss0] = v4;
        } else {
          bf16* hp = (seg == 0) ? o0 : o1b;
          #pragma unroll
          for (int rr=0;rr<4;rr++)
            hp[(((size_t)(bb*H_ + h))*S_ + ss0 + rr)*DH_ + dd] = (bf16)vv[rr];
        }
      } else {
        #pragma unroll
        for (int rr=0;rr<4;rr++){
          int gm = gm0 + rr;
          float v = vv[rr];
          if (pre)  pre[(size_t)gm*N + gn] = (bf16)v;
          if (bsc)  v = v*bsc[gn & 511] + bsh[gn & 511];
          if (relu) v = fmaxf(v, 0.f);
          if (of) of[(size_t)gm*N + gn] = v;
          else    o0[(size_t)gm*N + gn] = (bf16)v;
        }
      }
    }
  }
}

// ---------------- flash attention: XOR-swizzled LDS, T14 split-stage,
// wave-private Ps, XCD-affinity block map.
// Q [BH,S,64], K [BH,S,64], Vt [BH,64,S] -> out merged [B,S,512]  (all bf16)
__global__ __launch_bounds__(256,4) void attn(
    const bf16* __restrict__ Q, const bf16* __restrict__ Kx,
    const bf16* __restrict__ Vt, bf16* __restrict__ out, int causal)
{
  __shared__ bf16 Ks[64*64];   // logical [key][d], slot XOR (row&7)
  __shared__ bf16 Vs[64*64];   // logical [d][key], slot XOR (row&7)
  __shared__ bf16 Ps[4][16*64];
  int bid = blockIdx.x;
  int bh = bid & 255;          // all q-blocks of a head on one XCD
  int qb = bid >> 8;
  int b = bh >> 3, h = bh & 7;
  int tid = threadIdx.x, wave = tid>>6, lane = tid&63;
  int lhi = lane>>4, llo = lane&15;
  int l7 = llo & 7;
  const bf16* Qb = Q  + (size_t)bh*S_*DH_;
  const bf16* Kb = Kx + (size_t)bh*S_*DH_;
  const bf16* Vb = Vt + (size_t)bh*DH_*S_;

  bf16x8 qf[2];
  #pragma unroll
  for (int f=0; f<2; f++)
    qf[f] = *(const bf16x8*)&Qb[(size_t)(qb*64 + wave*16 + llo)*DH_ + f*32 + lhi*8];

  f32x4 oacc[4];
  #pragma unroll
  for (int f=0; f<4; f++) oacc[f] = (f32x4){0.f,0.f,0.f,0.f};
  float mrow[4], lrow4[4];
  #pragma unroll
  for (int r=0;r<4;r++){ mrow[r] = -1e9f; lrow4[r] = 0.f; }

  int KT = causal ? (qb+1) : (S_/64);

  int srow0 = tid>>3, sslot = tid&7;
  bf16x8 kreg[2], vreg[2];

  auto issue = [&](int kb){
    const bf16* kt0 = Kb + (size_t)kb*64*DH_;
    #pragma unroll
    for (int s=0;s<2;s++){
      int row = s*32 + srow0;
      kreg[s] = *(const bf16x8*)&kt0[(size_t)row*64 + sslot*8];
      vreg[s] = *(const bf16x8*)&Vb[(size_t)row*S_ + (size_t)kb*64 + sslot*8];
    }
  };
  issue(0);

  for (int kb=0; kb<KT; kb++){
    #pragma unroll
    for (int s=0;s<2;s++){
      int row = s*32 + srow0;
      int sl = sslot ^ (row&7);
      *(bf16x8*)&Ks[row*64 + sl*8] = kreg[s];
      *(bf16x8*)&Vs[row*64 + sl*8] = vreg[s];
    }
    __syncthreads();

    f32x4 sc[4];
    #pragma unroll
    for (int f=0; f<4; f++){
      f32x4 z = (f32x4){0.f,0.f,0.f,0.f};
      #pragma unroll
      for (int ks=0; ks<2; ks++){
        int row = f*16 + llo;
        int slot = (ks*4 + lhi) ^ (row&7);
        bf16x8 kf = *(const bf16x8*)&Ks[row*64 + slot*8];
        z = __builtin_amdgcn_mfma_f32_16x16x32_bf16(qf[ks], kf, z, 0,0,0);
      }
      sc[f] = z;
    }
    #pragma unroll
    for (int f=0; f<4; f++)
      #pragma unroll
      for (int r=0;r<4;r++){
        float v = sc[f][r]*0.125f;
        if (causal && kb==KT-1){
          int gcol = kb*64 + f*16 + llo;
          int grow = qb*64 + wave*16 + lhi*4 + r;
          if (gcol > grow) v = -1e9f;
        }
        sc[f][r] = v;
      }

    float alpha[4], psum[4];
    #pragma unroll
    for (int r=0;r<4;r++){
      float vm = fmaxf(fmaxf(sc[0][r],sc[1][r]), fmaxf(sc[2][r],sc[3][r]));
      #pragma unroll
      for (int msk=1; msk<16; msk<<=1) vm = fmaxf(vm, __shfl_xor(vm, msk));
      float mn = fmaxf(mrow[r], vm);
      alpha[r] = __expf(mrow[r]-mn);
      mrow[r]  = mn;
      psum[r]  = 0.f;
    }
    #pragma unroll
    for (int f=0; f<4; f++)
      #pragma unroll
      for (int r=0;r<4;r++){
        float p = __expf(sc[f][r]-mrow[r]);
        psum[r] += p;
        int row = lhi*4 + r;
        int slot = (f*2 + (llo>>3)) ^ (row&7);
        Ps[wave][row*64 + slot*8 + l7] = (bf16)p;
      }
    #pragma unroll
    for (int r=0;r<4;r++){
      float s = psum[r];
      #pragma unroll
      for (int msk=1; msk<16; msk<<=1) s += __shfl_xor(s, msk);
      lrow4[r] = lrow4[r]*alpha[r] + s;
      #pragma unroll
      for (int f=0; f<4; f++) oacc[f][r] *= alpha[r];
    }

    if (kb+1 < KT) issue(kb+1);

    asm volatile("s_waitcnt lgkmcnt(0)" ::: "memory");
    __builtin_amdgcn_sched_barrier(0);

    #pragma unroll
    for (int ks=0; ks<2; ks++){
      int pslot = (ks*4 + lhi) ^ l7;
      bf16x8 pf = *(const bf16x8*)&Ps[wave][llo*64 + pslot*8];
      #pragma unroll
      for (int f2=0; f2<4; f2++){
        int row = f2*16 + llo;
        int slot = (ks*4 + lhi) ^ (row&7);
        bf16x8 vf = *(const bf16x8*)&Vs[row*64 + slot*8];
        oacc[f2] = __builtin_amdgcn_mfma_f32_16x16x32_bf16(pf, vf, oacc[f2], 0,0,0);
      }
    }
    __syncthreads();
  }

  int qg = qb*64 + wave*16;
  #pragma unroll
  for (int f2=0; f2<4; f2++)
    #pragma unroll
    for (int r=0;r<4;r++){
      int row = qg + lhi*4 + r;
      int dd  = f2*16 + llo;
      out[((size_t)(b*S_ + row))*D_ + h*DH_ + dd] = (bf16)(oacc[f2][r] / lrow4[r]);
    }
}

// ------------------------------------------------------------------
extern "C" void kernel_launch(void* const* d_in, const int* in_sizes, int n_in,
                              void* d_out, int out_size, void* d_ws, size_t ws_size,
                              hipStream_t stream)
{
  (void)in_sizes; (void)n_in; (void)out_size; (void)ws_size;
  const float* enc = (const float*)d_in[0];
  const float* x2  = (const float*)d_in[1];
  const float* Wq1 = (const float*)d_in[2];  const float* bq1 = (const float*)d_in[3];
  const float* Wk1 = (const float*)d_in[4];  const float* bk1 = (const float*)d_in[5];
  const float* Wv1 = (const float*)d_in[6];  const float* bv1 = (const float*)d_in[7];
  const float* Wo1 = (const float*)d_in[8];  const float* bo1 = (const float*)d_in[9];
  const float* Wq2 = (const float*)d_in[10]; const float* bq2 = (const float*)d_in[11];
  const float* Wk2 = (const float*)d_in[12]; const float* bk2 = (const float*)d_in[13];
  const float* Wv2 = (const float*)d_in[14]; const float* bv2 = (const float*)d_in[15];
  const float* Wo2 = (const float*)d_in[16]; const float* bo2 = (const float*)d_in[17];
  const float* Wff1= (const float*)d_in[18]; const float* Wff2= (const float*)d_in[19];
  float* outp = (float*)d_out;

  char* ws = (char*)d_ws;
  size_t off = 0;
  auto alloc = [&](size_t bytes)->void*{ void* p = ws + off; off += (bytes+255)&~(size_t)255; return p; };
  bf16* Wt8   = (bf16*)alloc((size_t)8*512*512*2);
  bf16* Wff1t = (bf16*)alloc((size_t)DFF_*D_*2);
  bf16* Wff2t = (bf16*)alloc((size_t)D_*DFF_*2);
  float* bnsc = (float*)alloc(4*512*4);
  float* bnsh = (float*)alloc(4*512*4);
  size_t actB = (size_t)NTOK*D_*2;
  bf16* X2b  = (bf16*)alloc(actB);   // bf16(x2)
  bf16* Abuf = (bf16*)alloc(actB);   // q (head-split)
  bf16* Bbuf = (bf16*)alloc(actB);   // k (head-split)
  bf16* Cbuf = (bf16*)alloc(actB);   // attn out (merged)
  bf16* Dv   = (bf16*)alloc(actB);   // v^T [BH][64][S]
  bf16* E1   = (bf16*)alloc(actB);   // xn -> x3
  bf16* E2   = (bf16*)alloc(actB);   // y = bn2(enc); later reused as cross_out (E3)
  bf16* E3   = E2;                   // cross_out bf16 (E2 dead after kv2)
  bf16* Fbuf = Abuf;                 // ff1 [NTOK,DFF] overlays Abuf..Dv (48 MiB), dead by then

  bf16* Wtq1 = Wt8 + 0*262144;   // [1536,512] = q1|k1|v1
  bf16* Wto1 = Wt8 + 3*262144;
  bf16* Wtq2 = Wt8 + 4*262144;
  bf16* Wtk2 = Wt8 + 5*262144;   // [1024,512] = k2|v2
  bf16* Wto2 = Wt8 + 7*262144;

  Ptr8 p8;
  p8.s[0]=Wq1; p8.s[1]=Wk1; p8.s[2]=Wv1; p8.s[3]=Wo1;
  p8.s[4]=Wq2; p8.s[5]=Wk2; p8.s[6]=Wv2; p8.s[7]=Wo2;
  transpose_w8<<<dim3(8,8,8),256,0,stream>>>(p8, Wt8);
  transpose_rc<<<dim3(DFF_/64, D_/64),256,0,stream>>>(Wff1, Wff1t, D_, DFF_);
  transpose_rc<<<dim3(D_/64, DFF_/64),256,0,stream>>>(Wff2, Wff2t, DFF_, D_);

  Ptr16 p16;
  for (int i=0;i<16;i++) p16.p[i] = (const float*)d_in[20+i];
  bn_prep<<<4,512,0,stream>>>(p16, bnsc, bnsh);
  cvt2<<<dim3(NTOK*D_/4/256, 2),256,0,stream>>>(enc, x2, bnsc+512, bnsh+512, E2, X2b);

  auto gemm = [&](const bf16* Am, const bf16* W,
                  const float* bb0, const float* bb1, const float* bb2,
                  const bf16* residb, const float* sc, const float* sh,
                  bf16* oo0, bf16* oo1, bf16* vt, int vseg,
                  float* of, bf16* pre,
                  int N, int K, int relu, int mode){
    gemm_bt<<<(NTOK/64)*(N/128), 256, 0, stream>>>(Am, W, bb0, bb1, bb2, residb, sc, sh,
                                                   oo0, oo1, vt, vseg, of, pre,
                                                   NTOK, N, K, relu, mode);
  };

  // ---- self-attention (causal): fused QKV projection; V written transposed ----
  gemm(X2b, Wtq1, bq1, bk1, bv1, nullptr, nullptr, nullptr,
       Abuf, Bbuf, Dv, 2, nullptr, nullptr, 1536, 512, 0, 1);
  attn<<<(S_/64)*B_*H_, 256, 0, stream>>>(Abuf, Bbuf, Dv, Cbuf, 1);
  // xn = bn1(attn@Wo1 + bo1 + x2) -> E1
  gemm(Cbuf, Wto1, bo1, nullptr, nullptr, X2b, bnsc+0, bnsh+0,
       E1, nullptr, nullptr, -1, nullptr, nullptr, 512, 512, 0, 0);

  // ---- cross-attention: Q from E1; fused KV from E2 (V transposed) ----
  gemm(E1, Wtq2, bq2, nullptr, nullptr, nullptr, nullptr, nullptr,
       Abuf, nullptr, nullptr, -1, nullptr, nullptr, 512, 512, 0, 1);
  gemm(E2, Wtk2, bk2, bv2, nullptr, nullptr, nullptr, nullptr,
       Bbuf, nullptr, Dv, 1, nullptr, nullptr, 1024, 512, 0, 1);
  attn<<<(S_/64)*B_*H_, 256, 0, stream>>>(Abuf, Bbuf, Dv, Cbuf, 0);
  // cross_out(bf16) -> E3 (pre-bn); x3 = bn3(cross_out) -> E1
  gemm(Cbuf, Wto2, bo2, nullptr, nullptr, X2b, bnsc+2*512, bnsh+2*512,
       E1, nullptr, nullptr, -1, nullptr, E3, 512, 512, 0, 0);

  // ---- FFN ----
  gemm(E1, Wff1t, nullptr, nullptr, nullptr, nullptr, nullptr, nullptr,
       Fbuf, nullptr, nullptr, -1, nullptr, nullptr, DFF_, 512, 1, 0);
  // out = bn4(ff1@Wff2 + cross_out)
  gemm(Fbuf, Wff2t, nullptr, nullptr, nullptr, E3, bnsc+3*512, bnsh+3*512,
       nullptr, nullptr, nullptr, -1, outp, nullptr, 512, DFF_, 0, 0);
}

// Round 7
// 317.604 us; speedup vs baseline: 1.7550x; 1.0462x over previous
//
#include <hip/hip_runtime.h>
#include <cstdint>
#include <cstddef>

typedef __bf16 bf16;
typedef __bf16 bf16x8 __attribute__((ext_vector_type(8)));
typedef __bf16 bf16x4 __attribute__((ext_vector_type(4)));
typedef float  f32x4  __attribute__((ext_vector_type(4)));

#define B_   32
#define S_   384
#define D_   512
#define H_   8
#define DH_  64
#define DFF_ 2048
#define NTOK (B_*S_)

__device__ __forceinline__ void gload16(const void* g, void* l){
  __builtin_amdgcn_global_load_lds((__attribute__((address_space(1))) uint32_t*)(g),
                                   (__attribute__((address_space(3))) uint32_t*)(l), 16, 0, 0);
}

// ---------------- weight transpose: fp32 [K,N] -> bf16 [N,K] ----------------
struct Ptr8 { const float* s[8]; };
__global__ __launch_bounds__(256) void transpose_w8(Ptr8 ps, bf16* dst){
  __shared__ float t[64][65];
  int w = blockIdx.z;
  const float* src = ps.s[w];
  bf16* d = dst + (size_t)w*512*512;
  int tr = blockIdx.y*64, tc = blockIdx.x*64;
  for (int i=threadIdx.x; i<4096; i+=256){ int r=i>>6, c=i&63; t[r][c] = src[(size_t)(tr+r)*512 + tc+c]; }
  __syncthreads();
  for (int i=threadIdx.x; i<4096; i+=256){ int c=i>>6, r=i&63; d[(size_t)(tc+c)*512 + tr+r] = (bf16)t[r][c]; }
}

__global__ __launch_bounds__(256) void transpose_rc(const float* __restrict__ src, bf16* __restrict__ dst,
                                                    int R, int C){
  __shared__ float t[64][65];
  int tr = blockIdx.y*64, tc = blockIdx.x*64;
  for (int i=threadIdx.x; i<4096; i+=256){ int r=i>>6, c=i&63; t[r][c] = src[(size_t)(tr+r)*C + tc+c]; }
  __syncthreads();
  for (int i=threadIdx.x; i<4096; i+=256){ int c=i>>6, r=i&63; dst[(size_t)(tc+c)*R + tr+r] = (bf16)t[r][c]; }
}

// ---------------- BN scale/shift precompute: bn(x) = x*sc + sh ----------------
struct Ptr16 { const float* p[16]; };
__global__ __launch_bounds__(512) void bn_prep(Ptr16 q, float* sc, float* sh){
  int i = blockIdx.x;
  int n = threadIdx.x;
  float g = q.p[i*4+0][n];
  float b = q.p[i*4+1][n];
  float m = q.p[i*4+2][n];
  float v = q.p[i*4+3][n];
  float s = g * rsqrtf(v + 1e-3f);
  sc[i*512+n] = s;
  sh[i*512+n] = b - m*s;
}

// fused: y=0 -> bn2(enc) -> E2 ; y=1 -> bf16(x2) -> X2b
__global__ __launch_bounds__(256) void cvt2(const float* __restrict__ enc, const float* __restrict__ x2,
                                            const float* __restrict__ sc, const float* __restrict__ sh,
                                            bf16* __restrict__ E2, bf16* __restrict__ X2b){
  size_t e0 = ((size_t)blockIdx.x*256 + threadIdx.x)*4;
  if (blockIdx.y == 0){
    int n0 = (int)(e0 & (D_-1));
    f32x4 xv = *(const f32x4*)(enc + e0);
    bf16x4 ov;
    #pragma unroll
    for (int j=0;j<4;j++) ov[j] = (bf16)(xv[j]*sc[n0+j] + sh[n0+j]);
    *(bf16x4*)(E2 + e0) = ov;
  } else {
    f32x4 xv = *(const f32x4*)(x2 + e0);
    bf16x4 ov;
    #pragma unroll
    for (int j=0;j<4;j++) ov[j] = (bf16)xv[j];
    *(bf16x4*)(X2b + e0) = ov;
  }
}

// ---------------- 64x128 GEMM (N=512 shapes), BK=64, 2-phase dbuf, XOR swizzle ----------------
__global__ __launch_bounds__(256,3) void gemm_bt(
    const bf16* __restrict__ A, const bf16* __restrict__ Wt,
    const float* __restrict__ b0, const float* __restrict__ b1, const float* __restrict__ b2,
    const bf16* __restrict__ residb,
    const float* __restrict__ bsc, const float* __restrict__ bsh,
    bf16* __restrict__ o0, bf16* __restrict__ o1b,
    bf16* __restrict__ vt, int vseg,
    float* __restrict__ of, bf16* __restrict__ pre,
    int M, int N, int K, int relu, int mode)
{
  __shared__ bf16 As[2][64*64];
  __shared__ bf16 Bs[2][128*64];
  int nwg = gridDim.x;
  int cpx = nwg >> 3;
  int bid = blockIdx.x;
  int swz = (bid & 7)*cpx + (bid >> 3);
  int tiles_n = N >> 7;
  int tm = swz / tiles_n, tn = swz - tm*tiles_n;

  int tid = threadIdx.x, wave = tid>>6, lane = tid&63;
  int lhi = lane>>4, llo = lane&15;
  int lrow = lane>>3, lcol = lane&7;
  int wr = wave>>1, wc = wave&1;

  f32x4 acc[2][4];
  #pragma unroll
  for (int i=0;i<2;i++)
    #pragma unroll
    for (int j=0;j<4;j++) acc[i][j] = (f32x4){0.f,0.f,0.f,0.f};

  const bf16* Abase = A  + (size_t)(tm*64)  * K;
  const bf16* Bbase = Wt + (size_t)(tn*128) * K;

  int arow0 = wave*16, brow0 = wave*32;

  auto STAGE = [&](int buf, int kt){
    #pragma unroll
    for (int q=0;q<2;q++){
      int r = arow0 + q*8 + lrow;
      int s = lcol ^ (r&7);
      gload16(Abase + (size_t)r*K + kt + s*8, (char*)&As[buf][0] + wave*2048 + q*1024);
    }
    #pragma unroll
    for (int q=0;q<4;q++){
      int r = brow0 + q*8 + lrow;
      int s = lcol ^ (r&7);
      gload16(Bbase + (size_t)r*K + kt + s*8, (char*)&Bs[buf][0] + wave*4096 + q*1024);
    }
  };

  STAGE(0, 0);
  __syncthreads();
  int nt = K >> 6;
  int cur = 0;
  for (int t=0; t<nt; ++t){
    if (t+1 < nt) STAGE(cur^1, (t+1)<<6);
    #pragma unroll
    for (int ks=0; ks<2; ks++){
      bf16x8 af[2], bfr[4];
      #pragma unroll
      for (int i=0;i<2;i++){
        int row = wr*32 + i*16 + llo;
        int slot = (ks*4 + lhi) ^ (row&7);
        af[i] = *(const bf16x8*)&As[cur][row*64 + slot*8];
      }
      #pragma unroll
      for (int j=0;j<4;j++){
        int row = wc*64 + j*16 + llo;
        int slot = (ks*4 + lhi) ^ (row&7);
        bfr[j] = *(const bf16x8*)&Bs[cur][row*64 + slot*8];
      }
      #pragma unroll
      for (int i=0;i<2;i++)
        #pragma unroll
        for (int j=0;j<4;j++)
          acc[i][j] = __builtin_amdgcn_mfma_f32_16x16x32_bf16(af[i], bfr[j], acc[i][j], 0,0,0);
    }
    __syncthreads();
    cur ^= 1;
  }

  int m0 = tm*64 + wr*32, n0 = tn*128 + wc*64;
  #pragma unroll
  for (int i=0;i<2;i++){
    #pragma unroll
    for (int j=0;j<4;j++){
      int gn = n0 + j*16 + llo;
      float vv[4];
      #pragma unroll
      for (int rr=0;rr<4;rr++){
        int gm = m0 + i*16 + lhi*4 + rr;
        float v = acc[i][j][rr];
        if (b0){
          const float* bp = (gn < 512) ? b0 : ((gn < 1024) ? b1 : b2);
          v += bp[gn & 511];
        }
        if (residb) v += (float)residb[(size_t)gm*N + gn];
        vv[rr] = v;
      }
      int gm0 = m0 + i*16 + lhi*4;
      if (mode == 1){
        int seg = gn >> 9, cn = gn & 511;
        int h = cn >> 6, dd = cn & 63;
        int bb = gm0 / S_, ss0 = gm0 - bb*S_;
        if (seg == vseg){
          bf16x4 v4;
          #pragma unroll
          for (int rr=0;rr<4;rr++) v4[rr] = (bf16)vv[rr];
          *(bf16x4*)&vt[((size_t)(bb*H_ + h)*DH_ + dd)*S_ + ss0] = v4;
        } else {
          bf16* hp = (seg == 0) ? o0 : o1b;
          #pragma unroll
          for (int rr=0;rr<4;rr++)
            hp[(((size_t)(bb*H_ + h))*S_ + ss0 + rr)*DH_ + dd] = (bf16)vv[rr];
        }
      } else {
        #pragma unroll
        for (int rr=0;rr<4;rr++){
          int gm = gm0 + rr;
          float v = vv[rr];
          if (pre)  pre[(size_t)gm*N + gn] = (bf16)v;
          if (bsc)  v = v*bsc[gn & 511] + bsh[gn & 511];
          if (relu) v = fmaxf(v, 0.f);
          if (of) of[(size_t)gm*N + gn] = v;
          else    o0[(size_t)gm*N + gn] = (bf16)v;
        }
      }
    }
  }
}

// ---------------- 128x128 GEMM (N>=1024 shapes), BK=32, 2-phase dbuf, XOR swizzle ----------------
// m97 geometry (acc[4][4]/wave, 16 MFMA/K-step/wave) + 2-phase prefetch, 32 KB LDS -> 3 blocks/CU.
__global__ __launch_bounds__(256,3) void gemm_bt2(
    const bf16* __restrict__ A, const bf16* __restrict__ Wt,
    const float* __restrict__ b0, const float* __restrict__ b1, const float* __restrict__ b2,
    const bf16* __restrict__ residb,
    bf16* __restrict__ o0, bf16* __restrict__ o1b,
    bf16* __restrict__ vt, int vseg,
    int M, int N, int K, int relu, int mode)
{
  __shared__ bf16 As[2][128*32];
  __shared__ bf16 Bs[2][128*32];
  int nwg = gridDim.x;
  int cpx = nwg >> 3;
  int bid = blockIdx.x;
  int swz = (bid & 7)*cpx + (bid >> 3);
  int tiles_n = N >> 7;
  int tm = swz / tiles_n, tn = swz - tm*tiles_n;

  int tid = threadIdx.x, wave = tid>>6, lane = tid&63;
  int lhi = lane>>4, llo = lane&15;
  int srow = lane>>2, sslot = lane&3;
  int wr = wave>>1, wc = wave&1;

  f32x4 acc[4][4];
  #pragma unroll
  for (int i=0;i<4;i++)
    #pragma unroll
    for (int j=0;j<4;j++) acc[i][j] = (f32x4){0.f,0.f,0.f,0.f};

  const bf16* Abase = A  + (size_t)(tm*128) * K;
  const bf16* Bbase = Wt + (size_t)(tn*128) * K;

  auto STAGE = [&](int buf, int kt){
    #pragma unroll
    for (int q=0;q<2;q++){
      int r = wave*32 + q*16 + srow;
      int s = sslot ^ (r&3);
      gload16(Abase + (size_t)r*K + kt + s*8, (char*)&As[buf][0] + wave*2048 + q*1024);
    }
    #pragma unroll
    for (int q=0;q<2;q++){
      int r = wave*32 + q*16 + srow;
      int s = sslot ^ (r&3);
      gload16(Bbase + (size_t)r*K + kt + s*8, (char*)&Bs[buf][0] + wave*2048 + q*1024);
    }
  };

  STAGE(0, 0);
  __syncthreads();
  int nt = K >> 5;
  int cur = 0;
  for (int t=0; t<nt; ++t){
    if (t+1 < nt) STAGE(cur^1, (t+1)<<5);
    bf16x8 af[4], bfr[4];
    #pragma unroll
    for (int i=0;i<4;i++){
      int row = wr*64 + i*16 + llo;
      int slot = lhi ^ (row&3);
      af[i] = *(const bf16x8*)&As[cur][row*32 + slot*8];
    }
    #pragma unroll
    for (int j=0;j<4;j++){
      int row = wc*64 + j*16 + llo;
      int slot = lhi ^ (row&3);
      bfr[j] = *(const bf16x8*)&Bs[cur][row*32 + slot*8];
    }
    #pragma unroll
    for (int i=0;i<4;i++)
      #pragma unroll
      for (int j=0;j<4;j++)
        acc[i][j] = __builtin_amdgcn_mfma_f32_16x16x32_bf16(af[i], bfr[j], acc[i][j], 0,0,0);
    __syncthreads();
    cur ^= 1;
  }

  int m0 = tm*128 + wr*64, n0 = tn*128 + wc*64;
  #pragma unroll
  for (int i=0;i<4;i++){
    #pragma unroll
    for (int j=0;j<4;j++){
      int gn = n0 + j*16 + llo;
      float vv[4];
      #pragma unroll
      for (int rr=0;rr<4;rr++){
        int gm = m0 + i*16 + lhi*4 + rr;
        float v = acc[i][j][rr];
        if (b0){
          const float* bp = (gn < 512) ? b0 : ((gn < 1024) ? b1 : b2);
          v += bp[gn & 511];
        }
        if (residb) v += (float)residb[(size_t)gm*N + gn];
        vv[rr] = v;
      }
      int gm0 = m0 + i*16 + lhi*4;
      if (mode == 1){
        int seg = gn >> 9, cn = gn & 511;
        int h = cn >> 6, dd = cn & 63;
        int bb = gm0 / S_, ss0 = gm0 - bb*S_;
        if (seg == vseg){
          bf16x4 v4;
          #pragma unroll
          for (int rr=0;rr<4;rr++) v4[rr] = (bf16)vv[rr];
          *(bf16x4*)&vt[((size_t)(bb*H_ + h)*DH_ + dd)*S_ + ss0] = v4;
        } else {
          bf16* hp = (seg == 0) ? o0 : o1b;
          #pragma unroll
          for (int rr=0;rr<4;rr++)
            hp[(((size_t)(bb*H_ + h))*S_ + ss0 + rr)*DH_ + dd] = (bf16)vv[rr];
        }
      } else {
        #pragma unroll
        for (int rr=0;rr<4;rr++){
          int gm = gm0 + rr;
          float v = vv[rr];
          if (relu) v = fmaxf(v, 0.f);
          o0[(size_t)gm*N + gn] = (bf16)v;
        }
      }
    }
  }
}

// ---------------- flash attention: XOR-swizzled LDS, T14 split-stage,
// wave-private Ps, XCD-affinity block map.
__global__ __launch_bounds__(256,4) void attn(
    const bf16* __restrict__ Q, const bf16* __restrict__ Kx,
    const bf16* __restrict__ Vt, bf16* __restrict__ out, int causal)
{
  __shared__ bf16 Ks[64*64];
  __shared__ bf16 Vs[64*64];
  __shared__ bf16 Ps[4][16*64];
  int bid = blockIdx.x;
  int bh = bid & 255;
  int qb = bid >> 8;
  int b = bh >> 3, h = bh & 7;
  int tid = threadIdx.x, wave = tid>>6, lane = tid&63;
  int lhi = lane>>4, llo = lane&15;
  int l7 = llo & 7;
  const bf16* Qb = Q  + (size_t)bh*S_*DH_;
  const bf16* Kb = Kx + (size_t)bh*S_*DH_;
  const bf16* Vb = Vt + (size_t)bh*DH_*S_;

  bf16x8 qf[2];
  #pragma unroll
  for (int f=0; f<2; f++)
    qf[f] = *(const bf16x8*)&Qb[(size_t)(qb*64 + wave*16 + llo)*DH_ + f*32 + lhi*8];

  f32x4 oacc[4];
  #pragma unroll
  for (int f=0; f<4; f++) oacc[f] = (f32x4){0.f,0.f,0.f,0.f};
  float mrow[4], lrow4[4];
  #pragma unroll
  for (int r=0;r<4;r++){ mrow[r] = -1e9f; lrow4[r] = 0.f; }

  int KT = causal ? (qb+1) : (S_/64);

  int srow0 = tid>>3, sslot = tid&7;
  bf16x8 kreg[2], vreg[2];

  auto issue = [&](int kb){
    const bf16* kt0 = Kb + (size_t)kb*64*DH_;
    #pragma unroll
    for (int s=0;s<2;s++){
      int row = s*32 + srow0;
      kreg[s] = *(const bf16x8*)&kt0[(size_t)row*64 + sslot*8];
      vreg[s] = *(const bf16x8*)&Vb[(size_t)row*S_ + (size_t)kb*64 + sslot*8];
    }
  };
  issue(0);

  for (int kb=0; kb<KT; kb++){
    #pragma unroll
    for (int s=0;s<2;s++){
      int row = s*32 + srow0;
      int sl = sslot ^ (row&7);
      *(bf16x8*)&Ks[row*64 + sl*8] = kreg[s];
      *(bf16x8*)&Vs[row*64 + sl*8] = vreg[s];
    }
    __syncthreads();

    f32x4 sc[4];
    #pragma unroll
    for (int f=0; f<4; f++){
      f32x4 z = (f32x4){0.f,0.f,0.f,0.f};
      #pragma unroll
      for (int ks=0; ks<2; ks++){
        int row = f*16 + llo;
        int slot = (ks*4 + lhi) ^ (row&7);
        bf16x8 kf = *(const bf16x8*)&Ks[row*64 + slot*8];
        z = __builtin_amdgcn_mfma_f32_16x16x32_bf16(qf[ks], kf, z, 0,0,0);
      }
      sc[f] = z;
    }
    #pragma unroll
    for (int f=0; f<4; f++)
      #pragma unroll
      for (int r=0;r<4;r++){
        float v = sc[f][r]*0.125f;
        if (causal && kb==KT-1){
          int gcol = kb*64 + f*16 + llo;
          int grow = qb*64 + wave*16 + lhi*4 + r;
          if (gcol > grow) v = -1e9f;
        }
        sc[f][r] = v;
      }

    float alpha[4], psum[4];
    #pragma unroll
    for (int r=0;r<4;r++){
      float vm = fmaxf(fmaxf(sc[0][r],sc[1][r]), fmaxf(sc[2][r],sc[3][r]));
      #pragma unroll
      for (int msk=1; msk<16; msk<<=1) vm = fmaxf(vm, __shfl_xor(vm, msk));
      float mn = fmaxf(mrow[r], vm);
      alpha[r] = __expf(mrow[r]-mn);
      mrow[r]  = mn;
      psum[r]  = 0.f;
    }
    #pragma unroll
    for (int f=0; f<4; f++)
      #pragma unroll
      for (int r=0;r<4;r++){
        float p = __expf(sc[f][r]-mrow[r]);
        psum[r] += p;
        int row = lhi*4 + r;
        int slot = (f*2 + (llo>>3)) ^ (row&7);
        Ps[wave][row*64 + slot*8 + l7] = (bf16)p;
      }
    #pragma unroll
    for (int r=0;r<4;r++){
      float s = psum[r];
      #pragma unroll
      for (int msk=1; msk<16; msk<<=1) s += __shfl_xor(s, msk);
      lrow4[r] = lrow4[r]*alpha[r] + s;
      #pragma unroll
      for (int f=0; f<4; f++) oacc[f][r] *= alpha[r];
    }

    if (kb+1 < KT) issue(kb+1);

    asm volatile("s_waitcnt lgkmcnt(0)" ::: "memory");
    __builtin_amdgcn_sched_barrier(0);

    #pragma unroll
    for (int ks=0; ks<2; ks++){
      int pslot = (ks*4 + lhi) ^ l7;
      bf16x8 pf = *(const bf16x8*)&Ps[wave][llo*64 + pslot*8];
      #pragma unroll
      for (int f2=0; f2<4; f2++){
        int row = f2*16 + llo;
        int slot = (ks*4 + lhi) ^ (row&7);
        bf16x8 vf = *(const bf16x8*)&Vs[row*64 + slot*8];
        oacc[f2] = __builtin_amdgcn_mfma_f32_16x16x32_bf16(pf, vf, oacc[f2], 0,0,0);
      }
    }
    __syncthreads();
  }

  int qg = qb*64 + wave*16;
  #pragma unroll
  for (int f2=0; f2<4; f2++)
    #pragma unroll
    for (int r=0;r<4;r++){
      int row = qg + lhi*4 + r;
      int dd  = f2*16 + llo;
      out[((size_t)(b*S_ + row))*D_ + h*DH_ + dd] = (bf16)(oacc[f2][r] / lrow4[r]);
    }
}

// ------------------------------------------------------------------
extern "C" void kernel_launch(void* const* d_in, const int* in_sizes, int n_in,
                              void* d_out, int out_size, void* d_ws, size_t ws_size,
                              hipStream_t stream)
{
  (void)in_sizes; (void)n_in; (void)out_size; (void)ws_size;
  const float* enc = (const float*)d_in[0];
  const float* x2  = (const float*)d_in[1];
  const float* Wq1 = (const float*)d_in[2];  const float* bq1 = (const float*)d_in[3];
  const float* Wk1 = (const float*)d_in[4];  const float* bk1 = (const float*)d_in[5];
  const float* Wv1 = (const float*)d_in[6];  const float* bv1 = (const float*)d_in[7];
  const float* Wo1 = (const float*)d_in[8];  const float* bo1 = (const float*)d_in[9];
  const float* Wq2 = (const float*)d_in[10]; const float* bq2 = (const float*)d_in[11];
  const float* Wk2 = (const float*)d_in[12]; const float* bk2 = (const float*)d_in[13];
  const float* Wv2 = (const float*)d_in[14]; const float* bv2 = (const float*)d_in[15];
  const float* Wo2 = (const float*)d_in[16]; const float* bo2 = (const float*)d_in[17];
  const float* Wff1= (const float*)d_in[18]; const float* Wff2= (const float*)d_in[19];
  float* outp = (float*)d_out;

  char* ws = (char*)d_ws;
  size_t off = 0;
  auto alloc = [&](size_t bytes)->void*{ void* p = ws + off; off += (bytes+255)&~(size_t)255; return p; };
  bf16* Wt8   = (bf16*)alloc((size_t)8*512*512*2);
  bf16* Wff1t = (bf16*)alloc((size_t)DFF_*D_*2);
  bf16* Wff2t = (bf16*)alloc((size_t)D_*DFF_*2);
  float* bnsc = (float*)alloc(4*512*4);
  float* bnsh = (float*)alloc(4*512*4);
  size_t actB = (size_t)NTOK*D_*2;
  bf16* X2b  = (bf16*)alloc(actB);
  bf16* Abuf = (bf16*)alloc(actB);
  bf16* Bbuf = (bf16*)alloc(actB);
  bf16* Cbuf = (bf16*)alloc(actB);
  bf16* Dv   = (bf16*)alloc(actB);
  bf16* E1   = (bf16*)alloc(actB);
  bf16* E2   = (bf16*)alloc(actB);
  bf16* E3   = E2;                   // cross_out bf16 (E2 dead after kv2)
  bf16* Fbuf = Abuf;                 // ff1 [NTOK,DFF] overlays Abuf..Dv

  bf16* Wtq1 = Wt8 + 0*262144;   // [1536,512] = q1|k1|v1
  bf16* Wto1 = Wt8 + 3*262144;
  bf16* Wtq2 = Wt8 + 4*262144;
  bf16* Wtk2 = Wt8 + 5*262144;   // [1024,512] = k2|v2
  bf16* Wto2 = Wt8 + 7*262144;

  Ptr8 p8;
  p8.s[0]=Wq1; p8.s[1]=Wk1; p8.s[2]=Wv1; p8.s[3]=Wo1;
  p8.s[4]=Wq2; p8.s[5]=Wk2; p8.s[6]=Wv2; p8.s[7]=Wo2;
  transpose_w8<<<dim3(8,8,8),256,0,stream>>>(p8, Wt8);
  transpose_rc<<<dim3(DFF_/64, D_/64),256,0,stream>>>(Wff1, Wff1t, D_, DFF_);
  transpose_rc<<<dim3(D_/64, DFF_/64),256,0,stream>>>(Wff2, Wff2t, DFF_, D_);

  Ptr16 p16;
  for (int i=0;i<16;i++) p16.p[i] = (const float*)d_in[20+i];
  bn_prep<<<4,512,0,stream>>>(p16, bnsc, bnsh);
  cvt2<<<dim3(NTOK*D_/4/256, 2),256,0,stream>>>(enc, x2, bnsc+512, bnsh+512, E2, X2b);

  auto gemm = [&](const bf16* Am, const bf16* W,
                  const float* bb0, const float* bb1, const float* bb2,
                  const bf16* residb, const float* sc, const float* sh,
                  bf16* oo0, bf16* oo1, bf16* vt, int vseg,
                  float* of, bf16* pre,
                  int N, int K, int relu, int mode){
    gemm_bt<<<(NTOK/64)*(N/128), 256, 0, stream>>>(Am, W, bb0, bb1, bb2, residb, sc, sh,
                                                   oo0, oo1, vt, vseg, of, pre,
                                                   NTOK, N, K, relu, mode);
  };
  auto gemm2 = [&](const bf16* Am, const bf16* W,
                   const float* bb0, const float* bb1, const float* bb2,
                   bf16* oo0, bf16* oo1, bf16* vt, int vseg,
                   int N, int K, int relu, int mode){
    gemm_bt2<<<(NTOK/128)*(N/128), 256, 0, stream>>>(Am, W, bb0, bb1, bb2, nullptr,
                                                     oo0, oo1, vt, vseg,
                                                     NTOK, N, K, relu, mode);
  };

  // ---- self-attention (causal): fused QKV projection; V written transposed ----
  gemm2(X2b, Wtq1, bq1, bk1, bv1, Abuf, Bbuf, Dv, 2, 1536, 512, 0, 1);
  attn<<<(S_/64)*B_*H_, 256, 0, stream>>>(Abuf, Bbuf, Dv, Cbuf, 1);
  // xn = bn1(attn@Wo1 + bo1 + x2) -> E1
  gemm(Cbuf, Wto1, bo1, nullptr, nullptr, X2b, bnsc+0, bnsh+0,
       E1, nullptr, nullptr, -1, nullptr, nullptr, 512, 512, 0, 0);

  // ---- cross-attention: Q from E1; fused KV from E2 (V transposed) ----
  gemm(E1, Wtq2, bq2, nullptr, nullptr, nullptr, nullptr, nullptr,
       Abuf, nullptr, nullptr, -1, nullptr, nullptr, 512, 512, 0, 1);
  gemm2(E2, Wtk2, bk2, bv2, nullptr, Bbuf, nullptr, Dv, 1, 1024, 512, 0, 1);
  attn<<<(S_/64)*B_*H_, 256, 0, stream>>>(Abuf, Bbuf, Dv, Cbuf, 0);
  // cross_out(bf16) -> E3 (pre-bn); x3 = bn3(cross_out) -> E1
  gemm(Cbuf, Wto2, bo2, nullptr, nullptr, X2b, bnsc+2*512, bnsh+2*512,
       E1, nullptr, nullptr, -1, nullptr, E3, 512, 512, 0, 0);

  // ---- FFN ----
  gemm2(E1, Wff1t, nullptr, nullptr, nullptr, Fbuf, nullptr, nullptr, -1, DFF_, 512, 1, 0);
  // out = bn4(ff1@Wff2 + cross_out)
  gemm(Fbuf, Wff2t, nullptr, nullptr, nullptr, E3, bnsc+3*512, bnsh+3*512,
       nullptr, nullptr, nullptr, -1, outp, nullptr, 512, DFF_, 0, 0);
}

// Round 8
// 316.312 us; speedup vs baseline: 1.7622x; 1.0041x over previous
//
#include <hip/hip_runtime.h>
#include <cstdint>
#include <cstddef>

typedef __bf16 bf16;
typedef __bf16 bf16x8 __attribute__((ext_vector_type(8)));
typedef __bf16 bf16x4 __attribute__((ext_vector_type(4)));
typedef float  f32x4  __attribute__((ext_vector_type(4)));

#define B_   32
#define S_   384
#define D_   512
#define H_   8
#define DH_  64
#define DFF_ 2048
#define NTOK (B_*S_)

__device__ __forceinline__ void gload16(const void* g, void* l){
  __builtin_amdgcn_global_load_lds((__attribute__((address_space(1))) uint32_t*)(g),
                                   (__attribute__((address_space(3))) uint32_t*)(l), 16, 0, 0);
}

// ---------------- weight transpose: fp32 [K,N] -> bf16 [N,K] ----------------
struct Ptr8 { const float* s[8]; };
__global__ __launch_bounds__(256) void transpose_w8(Ptr8 ps, bf16* dst){
  __shared__ float t[64][65];
  int w = blockIdx.z;
  const float* src = ps.s[w];
  bf16* d = dst + (size_t)w*512*512;
  int tr = blockIdx.y*64, tc = blockIdx.x*64;
  for (int i=threadIdx.x; i<4096; i+=256){ int r=i>>6, c=i&63; t[r][c] = src[(size_t)(tr+r)*512 + tc+c]; }
  __syncthreads();
  for (int i=threadIdx.x; i<4096; i+=256){ int c=i>>6, r=i&63; d[(size_t)(tc+c)*512 + tr+r] = (bf16)t[r][c]; }
}

__global__ __launch_bounds__(256) void transpose_rc(const float* __restrict__ src, bf16* __restrict__ dst,
                                                    int R, int C){
  __shared__ float t[64][65];
  int tr = blockIdx.y*64, tc = blockIdx.x*64;
  for (int i=threadIdx.x; i<4096; i+=256){ int r=i>>6, c=i&63; t[r][c] = src[(size_t)(tr+r)*C + tc+c]; }
  __syncthreads();
  for (int i=threadIdx.x; i<4096; i+=256){ int c=i>>6, r=i&63; dst[(size_t)(tc+c)*R + tr+r] = (bf16)t[r][c]; }
}

// ---------------- BN scale/shift precompute: bn(x) = x*sc + sh ----------------
struct Ptr16 { const float* p[16]; };
__global__ __launch_bounds__(512) void bn_prep(Ptr16 q, float* sc, float* sh){
  int i = blockIdx.x;
  int n = threadIdx.x;
  float g = q.p[i*4+0][n];
  float b = q.p[i*4+1][n];
  float m = q.p[i*4+2][n];
  float v = q.p[i*4+3][n];
  float s = g * rsqrtf(v + 1e-3f);
  sc[i*512+n] = s;
  sh[i*512+n] = b - m*s;
}

// fused: y=0 -> bn2(enc) -> E2 ; y=1 -> bf16(x2) -> X2b
__global__ __launch_bounds__(256) void cvt2(const float* __restrict__ enc, const float* __restrict__ x2,
                                            const float* __restrict__ sc, const float* __restrict__ sh,
                                            bf16* __restrict__ E2, bf16* __restrict__ X2b){
  size_t e0 = ((size_t)blockIdx.x*256 + threadIdx.x)*4;
  if (blockIdx.y == 0){
    int n0 = (int)(e0 & (D_-1));
    f32x4 xv = *(const f32x4*)(enc + e0);
    bf16x4 ov;
    #pragma unroll
    for (int j=0;j<4;j++) ov[j] = (bf16)(xv[j]*sc[n0+j] + sh[n0+j]);
    *(bf16x4*)(E2 + e0) = ov;
  } else {
    f32x4 xv = *(const f32x4*)(x2 + e0);
    bf16x4 ov;
    #pragma unroll
    for (int j=0;j<4;j++) ov[j] = (bf16)xv[j];
    *(bf16x4*)(X2b + e0) = ov;
  }
}

// ---------------- 64x128 GEMM (N=512 shapes), BK=64, 2-phase dbuf, XOR swizzle ----------------
__global__ __launch_bounds__(256,3) void gemm_bt(
    const bf16* __restrict__ A, const bf16* __restrict__ Wt,
    const float* __restrict__ b0, const float* __restrict__ b1, const float* __restrict__ b2,
    const bf16* __restrict__ residb,
    const float* __restrict__ bsc, const float* __restrict__ bsh,
    bf16* __restrict__ o0, bf16* __restrict__ o1b,
    bf16* __restrict__ vt, int vseg,
    float* __restrict__ of, bf16* __restrict__ pre,
    int M, int N, int K, int relu, int mode)
{
  __shared__ bf16 As[2][64*64];
  __shared__ bf16 Bs[2][128*64];
  int nwg = gridDim.x;
  int cpx = nwg >> 3;
  int bid = blockIdx.x;
  int swz = (bid & 7)*cpx + (bid >> 3);
  int tiles_n = N >> 7;
  int tm = swz / tiles_n, tn = swz - tm*tiles_n;

  int tid = threadIdx.x, wave = tid>>6, lane = tid&63;
  int lhi = lane>>4, llo = lane&15;
  int lrow = lane>>3, lcol = lane&7;
  int wr = wave>>1, wc = wave&1;

  f32x4 acc[2][4];
  #pragma unroll
  for (int i=0;i<2;i++)
    #pragma unroll
    for (int j=0;j<4;j++) acc[i][j] = (f32x4){0.f,0.f,0.f,0.f};

  const bf16* Abase = A  + (size_t)(tm*64)  * K;
  const bf16* Bbase = Wt + (size_t)(tn*128) * K;

  int arow0 = wave*16, brow0 = wave*32;

  auto STAGE = [&](int buf, int kt){
    #pragma unroll
    for (int q=0;q<2;q++){
      int r = arow0 + q*8 + lrow;
      int s = lcol ^ (r&7);
      gload16(Abase + (size_t)r*K + kt + s*8, (char*)&As[buf][0] + wave*2048 + q*1024);
    }
    #pragma unroll
    for (int q=0;q<4;q++){
      int r = brow0 + q*8 + lrow;
      int s = lcol ^ (r&7);
      gload16(Bbase + (size_t)r*K + kt + s*8, (char*)&Bs[buf][0] + wave*4096 + q*1024);
    }
  };

  STAGE(0, 0);
  __syncthreads();
  int nt = K >> 6;
  int cur = 0;
  for (int t=0; t<nt; ++t){
    if (t+1 < nt) STAGE(cur^1, (t+1)<<6);
    #pragma unroll
    for (int ks=0; ks<2; ks++){
      bf16x8 af[2], bfr[4];
      #pragma unroll
      for (int i=0;i<2;i++){
        int row = wr*32 + i*16 + llo;
        int slot = (ks*4 + lhi) ^ (row&7);
        af[i] = *(const bf16x8*)&As[cur][row*64 + slot*8];
      }
      #pragma unroll
      for (int j=0;j<4;j++){
        int row = wc*64 + j*16 + llo;
        int slot = (ks*4 + lhi) ^ (row&7);
        bfr[j] = *(const bf16x8*)&Bs[cur][row*64 + slot*8];
      }
      #pragma unroll
      for (int i=0;i<2;i++)
        #pragma unroll
        for (int j=0;j<4;j++)
          acc[i][j] = __builtin_amdgcn_mfma_f32_16x16x32_bf16(af[i], bfr[j], acc[i][j], 0,0,0);
    }
    __syncthreads();
    cur ^= 1;
  }

  int m0 = tm*64 + wr*32, n0 = tn*128 + wc*64;
  #pragma unroll
  for (int i=0;i<2;i++){
    #pragma unroll
    for (int j=0;j<4;j++){
      int gn = n0 + j*16 + llo;
      float vv[4];
      #pragma unroll
      for (int rr=0;rr<4;rr++){
        int gm = m0 + i*16 + lhi*4 + rr;
        float v = acc[i][j][rr];
        if (b0){
          const float* bp = (gn < 512) ? b0 : ((gn < 1024) ? b1 : b2);
          v += bp[gn & 511];
        }
        if (residb) v += (float)residb[(size_t)gm*N + gn];
        vv[rr] = v;
      }
      int gm0 = m0 + i*16 + lhi*4;
      if (mode == 1){
        int seg = gn >> 9, cn = gn & 511;
        int h = cn >> 6, dd = cn & 63;
        int bb = gm0 / S_, ss0 = gm0 - bb*S_;
        if (seg == vseg){
          bf16x4 v4;
          #pragma unroll
          for (int rr=0;rr<4;rr++) v4[rr] = (bf16)vv[rr];
          *(bf16x4*)&vt[((size_t)(bb*H_ + h)*DH_ + dd)*S_ + ss0] = v4;
        } else {
          bf16* hp = (seg == 0) ? o0 : o1b;
          #pragma unroll
          for (int rr=0;rr<4;rr++)
            hp[(((size_t)(bb*H_ + h))*S_ + ss0 + rr)*DH_ + dd] = (bf16)vv[rr];
        }
      } else {
        #pragma unroll
        for (int rr=0;rr<4;rr++){
          int gm = gm0 + rr;
          float v = vv[rr];
          if (pre)  pre[(size_t)gm*N + gn] = (bf16)v;
          if (bsc)  v = v*bsc[gn & 511] + bsh[gn & 511];
          if (relu) v = fmaxf(v, 0.f);
          if (of) of[(size_t)gm*N + gn] = v;
          else    o0[(size_t)gm*N + gn] = (bf16)v;
        }
      }
    }
  }
}

// ---------------- 128x128 GEMM (N>=1024 shapes), BK=32, 2-phase dbuf ----------------
// Rows are 32 elem = 64 B => bank pattern repeats every 2 rows, so the XOR must use
// (row>>1)&3 (r&3 gives a 4-way conflict — measured 2.36M conflicts in round 7).
__global__ __launch_bounds__(256,4) void gemm_bt2(
    const bf16* __restrict__ A, const bf16* __restrict__ Wt,
    const float* __restrict__ b0, const float* __restrict__ b1, const float* __restrict__ b2,
    const bf16* __restrict__ residb,
    bf16* __restrict__ o0, bf16* __restrict__ o1b,
    bf16* __restrict__ vt, int vseg,
    int M, int N, int K, int relu, int mode)
{
  __shared__ bf16 As[2][128*32];
  __shared__ bf16 Bs[2][128*32];
  int nwg = gridDim.x;
  int cpx = nwg >> 3;
  int bid = blockIdx.x;
  int swz = (bid & 7)*cpx + (bid >> 3);
  int tiles_n = N >> 7;
  int tm = swz / tiles_n, tn = swz - tm*tiles_n;

  int tid = threadIdx.x, wave = tid>>6, lane = tid&63;
  int lhi = lane>>4, llo = lane&15;
  int srow = lane>>2, sslot = lane&3;
  int wr = wave>>1, wc = wave&1;

  f32x4 acc[4][4];
  #pragma unroll
  for (int i=0;i<4;i++)
    #pragma unroll
    for (int j=0;j<4;j++) acc[i][j] = (f32x4){0.f,0.f,0.f,0.f};

  const bf16* Abase = A  + (size_t)(tm*128) * K;
  const bf16* Bbase = Wt + (size_t)(tn*128) * K;

  auto STAGE = [&](int buf, int kt){
    #pragma unroll
    for (int q=0;q<2;q++){
      int r = wave*32 + q*16 + srow;
      int s = sslot ^ ((r>>1)&3);
      gload16(Abase + (size_t)r*K + kt + s*8, (char*)&As[buf][0] + wave*2048 + q*1024);
    }
    #pragma unroll
    for (int q=0;q<2;q++){
      int r = wave*32 + q*16 + srow;
      int s = sslot ^ ((r>>1)&3);
      gload16(Bbase + (size_t)r*K + kt + s*8, (char*)&Bs[buf][0] + wave*2048 + q*1024);
    }
  };

  STAGE(0, 0);
  __syncthreads();
  int nt = K >> 5;
  int cur = 0;
  for (int t=0; t<nt; ++t){
    if (t+1 < nt) STAGE(cur^1, (t+1)<<5);
    bf16x8 af[4], bfr[4];
    #pragma unroll
    for (int i=0;i<4;i++){
      int row = wr*64 + i*16 + llo;
      int slot = lhi ^ ((row>>1)&3);
      af[i] = *(const bf16x8*)&As[cur][row*32 + slot*8];
    }
    #pragma unroll
    for (int j=0;j<4;j++){
      int row = wc*64 + j*16 + llo;
      int slot = lhi ^ ((row>>1)&3);
      bfr[j] = *(const bf16x8*)&Bs[cur][row*32 + slot*8];
    }
    #pragma unroll
    for (int i=0;i<4;i++)
      #pragma unroll
      for (int j=0;j<4;j++)
        acc[i][j] = __builtin_amdgcn_mfma_f32_16x16x32_bf16(af[i], bfr[j], acc[i][j], 0,0,0);
    __syncthreads();
    cur ^= 1;
  }

  int m0 = tm*128 + wr*64, n0 = tn*128 + wc*64;
  #pragma unroll
  for (int i=0;i<4;i++){
    #pragma unroll
    for (int j=0;j<4;j++){
      int gn = n0 + j*16 + llo;
      float vv[4];
      #pragma unroll
      for (int rr=0;rr<4;rr++){
        int gm = m0 + i*16 + lhi*4 + rr;
        float v = acc[i][j][rr];
        if (b0){
          const float* bp = (gn < 512) ? b0 : ((gn < 1024) ? b1 : b2);
          v += bp[gn & 511];
        }
        if (residb) v += (float)residb[(size_t)gm*N + gn];
        vv[rr] = v;
      }
      int gm0 = m0 + i*16 + lhi*4;
      if (mode == 1){
        int seg = gn >> 9, cn = gn & 511;
        int h = cn >> 6, dd = cn & 63;
        int bb = gm0 / S_, ss0 = gm0 - bb*S_;
        if (seg == vseg){
          bf16x4 v4;
          #pragma unroll
          for (int rr=0;rr<4;rr++) v4[rr] = (bf16)vv[rr];
          *(bf16x4*)&vt[((size_t)(bb*H_ + h)*DH_ + dd)*S_ + ss0] = v4;
        } else {
          bf16* hp = (seg == 0) ? o0 : o1b;
          #pragma unroll
          for (int rr=0;rr<4;rr++)
            hp[(((size_t)(bb*H_ + h))*S_ + ss0 + rr)*DH_ + dd] = (bf16)vv[rr];
        }
      } else {
        #pragma unroll
        for (int rr=0;rr<4;rr++){
          int gm = gm0 + rr;
          float v = vv[rr];
          if (relu) v = fmaxf(v, 0.f);
          o0[(size_t)gm*N + gn] = (bf16)v;
        }
      }
    }
  }
}

// ---------------- flash attention: XOR-swizzled LDS, T14 split-stage,
// wave-private Ps, XCD-affinity block map.
__global__ __launch_bounds__(256,4) void attn(
    const bf16* __restrict__ Q, const bf16* __restrict__ Kx,
    const bf16* __restrict__ Vt, bf16* __restrict__ out, int causal)
{
  __shared__ bf16 Ks[64*64];
  __shared__ bf16 Vs[64*64];
  __shared__ bf16 Ps[4][16*64];
  int bid = blockIdx.x;
  int bh = bid & 255;
  int qb = bid >> 8;
  int b = bh >> 3, h = bh & 7;
  int tid = threadIdx.x, wave = tid>>6, lane = tid&63;
  int lhi = lane>>4, llo = lane&15;
  int l7 = llo & 7;
  const bf16* Qb = Q  + (size_t)bh*S_*DH_;
  const bf16* Kb = Kx + (size_t)bh*S_*DH_;
  const bf16* Vb = Vt + (size_t)bh*DH_*S_;

  bf16x8 qf[2];
  #pragma unroll
  for (int f=0; f<2; f++)
    qf[f] = *(const bf16x8*)&Qb[(size_t)(qb*64 + wave*16 + llo)*DH_ + f*32 + lhi*8];

  f32x4 oacc[4];
  #pragma unroll
  for (int f=0; f<4; f++) oacc[f] = (f32x4){0.f,0.f,0.f,0.f};
  float mrow[4], lrow4[4];
  #pragma unroll
  for (int r=0;r<4;r++){ mrow[r] = -1e9f; lrow4[r] = 0.f; }

  int KT = causal ? (qb+1) : (S_/64);

  int srow0 = tid>>3, sslot = tid&7;
  bf16x8 kreg[2], vreg[2];

  auto issue = [&](int kb){
    const bf16* kt0 = Kb + (size_t)kb*64*DH_;
    #pragma unroll
    for (int s=0;s<2;s++){
      int row = s*32 + srow0;
      kreg[s] = *(const bf16x8*)&kt0[(size_t)row*64 + sslot*8];
      vreg[s] = *(const bf16x8*)&Vb[(size_t)row*S_ + (size_t)kb*64 + sslot*8];
    }
  };
  issue(0);

  for (int kb=0; kb<KT; kb++){
    #pragma unroll
    for (int s=0;s<2;s++){
      int row = s*32 + srow0;
      int sl = sslot ^ (row&7);
      *(bf16x8*)&Ks[row*64 + sl*8] = kreg[s];
      *(bf16x8*)&Vs[row*64 + sl*8] = vreg[s];
    }
    __syncthreads();

    f32x4 sc[4];
    #pragma unroll
    for (int f=0; f<4; f++){
      f32x4 z = (f32x4){0.f,0.f,0.f,0.f};
      #pragma unroll
      for (int ks=0; ks<2; ks++){
        int row = f*16 + llo;
        int slot = (ks*4 + lhi) ^ (row&7);
        bf16x8 kf = *(const bf16x8*)&Ks[row*64 + slot*8];
        z = __builtin_amdgcn_mfma_f32_16x16x32_bf16(qf[ks], kf, z, 0,0,0);
      }
      sc[f] = z;
    }
    #pragma unroll
    for (int f=0; f<4; f++)
      #pragma unroll
      for (int r=0;r<4;r++){
        float v = sc[f][r]*0.125f;
        if (causal && kb==KT-1){
          int gcol = kb*64 + f*16 + llo;
          int grow = qb*64 + wave*16 + lhi*4 + r;
          if (gcol > grow) v = -1e9f;
        }
        sc[f][r] = v;
      }

    float alpha[4], psum[4];
    #pragma unroll
    for (int r=0;r<4;r++){
      float vm = fmaxf(fmaxf(sc[0][r],sc[1][r]), fmaxf(sc[2][r],sc[3][r]));
      #pragma unroll
      for (int msk=1; msk<16; msk<<=1) vm = fmaxf(vm, __shfl_xor(vm, msk));
      float mn = fmaxf(mrow[r], vm);
      alpha[r] = __expf(mrow[r]-mn);
      mrow[r]  = mn;
      psum[r]  = 0.f;
    }
    #pragma unroll
    for (int f=0; f<4; f++)
      #pragma unroll
      for (int r=0;r<4;r++){
        float p = __expf(sc[f][r]-mrow[r]);
        psum[r] += p;
        int row = lhi*4 + r;
        int slot = (f*2 + (llo>>3)) ^ (row&7);
        Ps[wave][row*64 + slot*8 + l7] = (bf16)p;
      }
    #pragma unroll
    for (int r=0;r<4;r++){
      float s = psum[r];
      #pragma unroll
      for (int msk=1; msk<16; msk<<=1) s += __shfl_xor(s, msk);
      lrow4[r] = lrow4[r]*alpha[r] + s;
      #pragma unroll
      for (int f=0; f<4; f++) oacc[f][r] *= alpha[r];
    }

    if (kb+1 < KT) issue(kb+1);

    asm volatile("s_waitcnt lgkmcnt(0)" ::: "memory");
    __builtin_amdgcn_sched_barrier(0);

    #pragma unroll
    for (int ks=0; ks<2; ks++){
      int pslot = (ks*4 + lhi) ^ l7;
      bf16x8 pf = *(const bf16x8*)&Ps[wave][llo*64 + pslot*8];
      #pragma unroll
      for (int f2=0; f2<4; f2++){
        int row = f2*16 + llo;
        int slot = (ks*4 + lhi) ^ (row&7);
        bf16x8 vf = *(const bf16x8*)&Vs[row*64 + slot*8];
        oacc[f2] = __builtin_amdgcn_mfma_f32_16x16x32_bf16(pf, vf, oacc[f2], 0,0,0);
      }
    }
    __syncthreads();
  }

  int qg = qb*64 + wave*16;
  #pragma unroll
  for (int f2=0; f2<4; f2++)
    #pragma unroll
    for (int r=0;r<4;r++){
      int row = qg + lhi*4 + r;
      int dd  = f2*16 + llo;
      out[((size_t)(b*S_ + row))*D_ + h*DH_ + dd] = (bf16)(oacc[f2][r] / lrow4[r]);
    }
}

// ------------------------------------------------------------------
extern "C" void kernel_launch(void* const* d_in, const int* in_sizes, int n_in,
                              void* d_out, int out_size, void* d_ws, size_t ws_size,
                              hipStream_t stream)
{
  (void)in_sizes; (void)n_in; (void)out_size; (void)ws_size;
  const float* enc = (const float*)d_in[0];
  const float* x2  = (const float*)d_in[1];
  const float* Wq1 = (const float*)d_in[2];  const float* bq1 = (const float*)d_in[3];
  const float* Wk1 = (const float*)d_in[4];  const float* bk1 = (const float*)d_in[5];
  const float* Wv1 = (const float*)d_in[6];  const float* bv1 = (const float*)d_in[7];
  const float* Wo1 = (const float*)d_in[8];  const float* bo1 = (const float*)d_in[9];
  const float* Wq2 = (const float*)d_in[10]; const float* bq2 = (const float*)d_in[11];
  const float* Wk2 = (const float*)d_in[12]; const float* bk2 = (const float*)d_in[13];
  const float* Wv2 = (const float*)d_in[14]; const float* bv2 = (const float*)d_in[15];
  const float* Wo2 = (const float*)d_in[16]; const float* bo2 = (const float*)d_in[17];
  const float* Wff1= (const float*)d_in[18]; const float* Wff2= (const float*)d_in[19];
  float* outp = (float*)d_out;

  char* ws = (char*)d_ws;
  size_t off = 0;
  auto alloc = [&](size_t bytes)->void*{ void* p = ws + off; off += (bytes+255)&~(size_t)255; return p; };
  bf16* Wt8   = (bf16*)alloc((size_t)8*512*512*2);
  bf16* Wff1t = (bf16*)alloc((size_t)DFF_*D_*2);
  bf16* Wff2t = (bf16*)alloc((size_t)D_*DFF_*2);
  float* bnsc = (float*)alloc(4*512*4);
  float* bnsh = (float*)alloc(4*512*4);
  size_t actB = (size_t)NTOK*D_*2;
  bf16* X2b  = (bf16*)alloc(actB);
  bf16* Abuf = (bf16*)alloc(actB);
  bf16* Bbuf = (bf16*)alloc(actB);
  bf16* Cbuf = (bf16*)alloc(actB);
  bf16* Dv   = (bf16*)alloc(actB);
  bf16* E1   = (bf16*)alloc(actB);
  bf16* E2   = (bf16*)alloc(actB);
  bf16* E3   = E2;                   // cross_out bf16 (E2 dead after kv2)
  bf16* Fbuf = Abuf;                 // ff1 [NTOK,DFF] overlays Abuf..Dv

  bf16* Wtq1 = Wt8 + 0*262144;   // [1536,512] = q1|k1|v1
  bf16* Wto1 = Wt8 + 3*262144;
  bf16* Wtq2 = Wt8 + 4*262144;
  bf16* Wtk2 = Wt8 + 5*262144;   // [1024,512] = k2|v2
  bf16* Wto2 = Wt8 + 7*262144;

  Ptr8 p8;
  p8.s[0]=Wq1; p8.s[1]=Wk1; p8.s[2]=Wv1; p8.s[3]=Wo1;
  p8.s[4]=Wq2; p8.s[5]=Wk2; p8.s[6]=Wv2; p8.s[7]=Wo2;
  transpose_w8<<<dim3(8,8,8),256,0,stream>>>(p8, Wt8);
  transpose_rc<<<dim3(DFF_/64, D_/64),256,0,stream>>>(Wff1, Wff1t, D_, DFF_);
  transpose_rc<<<dim3(D_/64, DFF_/64),256,0,stream>>>(Wff2, Wff2t, DFF_, D_);

  Ptr16 p16;
  for (int i=0;i<16;i++) p16.p[i] = (const float*)d_in[20+i];
  bn_prep<<<4,512,0,stream>>>(p16, bnsc, bnsh);
  cvt2<<<dim3(NTOK*D_/4/256, 2),256,0,stream>>>(enc, x2, bnsc+512, bnsh+512, E2, X2b);

  auto gemm = [&](const bf16* Am, const bf16* W,
                  const float* bb0, const float* bb1, const float* bb2,
                  const bf16* residb, const float* sc, const float* sh,
                  bf16* oo0, bf16* oo1, bf16* vt, int vseg,
                  float* of, bf16* pre,
                  int N, int K, int relu, int mode){
    gemm_bt<<<(NTOK/64)*(N/128), 256, 0, stream>>>(Am, W, bb0, bb1, bb2, residb, sc, sh,
                                                   oo0, oo1, vt, vseg, of, pre,
                                                   NTOK, N, K, relu, mode);
  };
  auto gemm2 = [&](const bf16* Am, const bf16* W,
                   const float* bb0, const float* bb1, const float* bb2,
                   bf16* oo0, bf16* oo1, bf16* vt, int vseg,
                   int N, int K, int relu, int mode){
    gemm_bt2<<<(NTOK/128)*(N/128), 256, 0, stream>>>(Am, W, bb0, bb1, bb2, nullptr,
                                                     oo0, oo1, vt, vseg,
                                                     NTOK, N, K, relu, mode);
  };

  // ---- self-attention (causal): fused QKV projection; V written transposed ----
  gemm2(X2b, Wtq1, bq1, bk1, bv1, Abuf, Bbuf, Dv, 2, 1536, 512, 0, 1);
  attn<<<(S_/64)*B_*H_, 256, 0, stream>>>(Abuf, Bbuf, Dv, Cbuf, 1);
  // xn = bn1(attn@Wo1 + bo1 + x2) -> E1
  gemm(Cbuf, Wto1, bo1, nullptr, nullptr, X2b, bnsc+0, bnsh+0,
       E1, nullptr, nullptr, -1, nullptr, nullptr, 512, 512, 0, 0);

  // ---- cross-attention: Q from E1; fused KV from E2 (V transposed) ----
  gemm(E1, Wtq2, bq2, nullptr, nullptr, nullptr, nullptr, nullptr,
       Abuf, nullptr, nullptr, -1, nullptr, nullptr, 512, 512, 0, 1);
  gemm2(E2, Wtk2, bk2, bv2, nullptr, Bbuf, nullptr, Dv, 1, 1024, 512, 0, 1);
  attn<<<(S_/64)*B_*H_, 256, 0, stream>>>(Abuf, Bbuf, Dv, Cbuf, 0);
  // cross_out(bf16) -> E3 (pre-bn); x3 = bn3(cross_out) -> E1
  gemm(Cbuf, Wto2, bo2, nullptr, nullptr, X2b, bnsc+2*512, bnsh+2*512,
       E1, nullptr, nullptr, -1, nullptr, E3, 512, 512, 0, 0);

  // ---- FFN ----
  gemm2(E1, Wff1t, nullptr, nullptr, nullptr, Fbuf, nullptr, nullptr, -1, DFF_, 512, 1, 0);
  // out = bn4(ff1@Wff2 + cross_out)
  gemm(Fbuf, Wff2t, nullptr, nullptr, nullptr, E3, bnsc+3*512, bnsh+3*512,
       nullptr, nullptr, nullptr, -1, outp, nullptr, 512, DFF_, 0, 0);
}